// Round 2
// baseline (4795.533 us; speedup 1.0000x reference)
//
#include <hip/hip_runtime.h>
#include <hip/hip_bf16.h>

#define NUSERS 100000
#define NTXN   200000
#define NEDGE  1000000
#define HD     64
#define NLAYER 3

// ---------------- dtype detection ----------------
// Interpret first `n` elements of x as bf16; if any |v| >= 1e4 or NaN, the
// underlying data must be fp32 (mantissa bits misread as exponent) -> flag=0.
// True bf16 N(0,1) data stays small -> flag=1.
__global__ void detect_dtype(const unsigned short* __restrict__ x, int* __restrict__ flag, int n) {
    __shared__ int s_big;
    if (threadIdx.x == 0) s_big = 0;
    __syncthreads();
    int big = 0;
    for (int i = threadIdx.x; i < n; i += blockDim.x) {
        float v = __uint_as_float(((unsigned int)x[i]) << 16);
        v = fabsf(v);
        if (!(v < 1.0e4f)) big = 1;  // catches huge and NaN
    }
    if (big) atomicAdd(&s_big, 1);
    __syncthreads();
    if (threadIdx.x == 0) flag[0] = (s_big > 0) ? 0 : 1;
}

// flag==1: src is bf16 ; flag==0: src is fp32
__global__ void cvt_to_f32(const void* __restrict__ src, float* __restrict__ dst, int n,
                           const int* __restrict__ flag) {
    int i = blockIdx.x * blockDim.x + threadIdx.x;
    if (i >= n) return;
    if (flag[0]) {
        unsigned short u = ((const unsigned short*)src)[i];
        dst[i] = __uint_as_float(((unsigned int)u) << 16);
    } else {
        dst[i] = ((const float*)src)[i];
    }
}

// ---------------- degree / norm kernels ----------------
__global__ void count_deg(const int* __restrict__ idx, float* __restrict__ deg, int n) {
    int i = blockIdx.x * blockDim.x + threadIdx.x;
    if (i < n) atomicAdd(&deg[idx[i]], 1.0f);
}

__global__ void finalize_dinv_selfloop(float* deg, int n) {
    int i = blockIdx.x * blockDim.x + threadIdx.x;
    if (i < n) deg[i] = rsqrtf(deg[i] + 1.0f);
}

__global__ void finalize_dinv(float* deg, int n) {
    int i = blockIdx.x * blockDim.x + threadIdx.x;
    if (i < n) { float d = deg[i]; deg[i] = (d > 0.f) ? rsqrtf(d) : 0.f; }
}

// ---------------- embedding GEMM: out[N x 64] = x[N x K] @ W[K x 64] + b ----
// x dtype resolved at runtime via flag; W/b already fp32-converted.
template <int K>
__global__ __launch_bounds__(256) void gemm_embed(const void* __restrict__ x,
                                                  const float* __restrict__ W,
                                                  const float* __restrict__ bias,
                                                  float* __restrict__ out, int N,
                                                  const int* __restrict__ flag) {
    const int lane = threadIdx.x & 63;
    float w[K];
#pragma unroll
    for (int k = 0; k < K; ++k) w[k] = W[k * HD + lane];
    const float b = bias[lane];
    const bool isb = flag[0] != 0;
    const int wid = (blockIdx.x << 2) + (threadIdx.x >> 6);
    const int stride = gridDim.x << 2;
    if (isb) {
        const unsigned short* xb = (const unsigned short*)x;
        for (int r = wid; r < N; r += stride) {
            const unsigned short* xr = xb + (size_t)r * K;
            float acc = b;
#pragma unroll
            for (int k = 0; k < K; ++k)
                acc = fmaf(__uint_as_float(((unsigned int)xr[k]) << 16), w[k], acc);
            out[(size_t)r * HD + lane] = acc;
        }
    } else {
        const float* xf = (const float*)x;
        for (int r = wid; r < N; r += stride) {
            const float* xr = xf + (size_t)r * K;
            float acc = b;
#pragma unroll
            for (int k = 0; k < K; ++k) acc = fmaf(xr[k], w[k], acc);
            out[(size_t)r * HD + lane] = acc;
        }
    }
}

// ---------------- layer GEMM (all fp32): out = h @ W ----------------
__global__ __launch_bounds__(256) void gemm_f32(const float* __restrict__ h,
                                                const float* __restrict__ W,
                                                float* __restrict__ out, int N) {
    const int lane = threadIdx.x & 63;
    float w[HD];
#pragma unroll
    for (int k = 0; k < HD; ++k) w[k] = W[k * HD + lane];
    const int wid = (blockIdx.x << 2) + (threadIdx.x >> 6);
    const int stride = gridDim.x << 2;
    for (int r = wid; r < N; r += stride) {
        const float* hr = h + (size_t)r * HD;
        float acc = 0.f;
#pragma unroll
        for (int k = 0; k < HD; ++k) acc = fmaf(hr[k], w[k], acc);
        out[(size_t)r * HD + lane] = acc;
    }
}

// ---------------- init acc rows with sum of two biases (fp32) ----------------
__global__ void init_acc(float* __restrict__ acc, const float* __restrict__ ba,
                         const float* __restrict__ bb, int ntot) {
    int i = blockIdx.x * blockDim.x + threadIdx.x;
    if (i < ntot) {
        int f = i & 63;
        acc[i] = ba[f] + bb[f];
    }
}

// ---------------- edge scatter: acc[dst] += m[src] * dis[src]*did[dst] --------
__global__ __launch_bounds__(256) void scatter_edges(const float* __restrict__ m,
                                                     const int* __restrict__ src,
                                                     const int* __restrict__ dst,
                                                     const float* __restrict__ dis,
                                                     const float* __restrict__ did,
                                                     float* __restrict__ acc, int E) {
    const int lane = threadIdx.x & 63;
    const int e = (blockIdx.x << 2) + (threadIdx.x >> 6);
    if (e >= E) return;
    const int s = src[e];
    const int d = dst[e];
    const float nrm = dis[s] * did[d];
    const float v = m[(size_t)s * HD + lane] * nrm;
    atomicAdd(&acc[(size_t)d * HD + lane], v);
}

// ---------------- self-loop: acc[i] += dinv[i]^2 * m[i] ----------------
__global__ __launch_bounds__(256) void selfloop_add(const float* __restrict__ m,
                                                    const float* __restrict__ dinv,
                                                    float* __restrict__ acc, int n) {
    const int lane = threadIdx.x & 63;
    const int i = (blockIdx.x << 2) + (threadIdx.x >> 6);
    if (i >= n) return;
    const float di = dinv[i];
    acc[(size_t)i * HD + lane] += di * di * m[(size_t)i * HD + lane];
}

// ---------------- h = relu(acc * 0.5) ----------------
__global__ void relu_half(const float* __restrict__ acc, float* __restrict__ h, int ntot) {
    int i = blockIdx.x * blockDim.x + threadIdx.x;
    if (i < ntot) h[i] = fmaxf(acc[i] * 0.5f, 0.f);
}

// ---------------- column mean (scaled) into gsum[64] ----------------
__global__ __launch_bounds__(256) void colmean(const float* __restrict__ h, int n, float scale,
                                               float* __restrict__ gsum) {
    const int lane = threadIdx.x & 63;
    const int w = threadIdx.x >> 6;
    float s = 0.f;
    for (int r = blockIdx.x * 4 + w; r < n; r += gridDim.x * 4)
        s += h[(size_t)r * HD + lane];
    __shared__ float red[256];
    red[threadIdx.x] = s;
    __syncthreads();
    if (threadIdx.x < 64) {
        float t = red[threadIdx.x] + red[64 + threadIdx.x] + red[128 + threadIdx.x] +
                  red[192 + threadIdx.x];
        atomicAdd(&gsum[lane], t * scale);
    }
}

// ---------------- head MLP: out = sigmoid(relu(g@W1+b1)@W2+b2) ----------------
__global__ void head(const float* __restrict__ g, const float* __restrict__ W1,
                     const float* __restrict__ b1, const float* __restrict__ W2,
                     const float* __restrict__ b2, const int* __restrict__ flag,
                     void* __restrict__ out) {
    const int c = threadIdx.x;  // 0..63, one wave
    float x = b1[c];
    for (int k = 0; k < HD; ++k) x = fmaf(g[k], W1[k * HD + c], x);
    x = fmaxf(x, 0.f);
    float t = x * W2[c];
    for (int off = 32; off; off >>= 1) t += __shfl_down(t, off);
    if (c == 0) {
        float z = t + b2[0];
        float s = 1.f / (1.f + expf(-z));
        if (flag[0]) {
            *(__hip_bfloat16*)out = __float2bfloat16(s);
        } else {
            *(float*)out = s;
        }
    }
}

extern "C" void kernel_launch(void* const* d_in, const int* in_sizes, int n_in,
                              void* d_out, int out_size, void* d_ws, size_t ws_size,
                              hipStream_t stream) {
    const void* x_user = d_in[0];
    const void* x_txn  = d_in[1];
    const int* ei_u2u = (const int*)d_in[2];
    const int* ei_t2t = (const int*)d_in[3];
    const int* ei_u2t = (const int*)d_in[4];
    const int* ei_t2u = (const int*)d_in[5];

    // ---- workspace layout (fp32) ----
    float* ws = (float*)d_ws;
    float* hu   = ws;                          // NU*64
    float* ht   = hu + (size_t)NUSERS * HD;    // NT*64
    float* mbuf = ht + (size_t)NTXN * HD;      // NT*64
    float* accU = mbuf + (size_t)NTXN * HD;    // NU*64
    float* accT = accU + (size_t)NUSERS * HD;  // NT*64
    float* dinv_u2u = accT + (size_t)NTXN * HD;  // NU
    float* dinv_t2t = dinv_u2u + NUSERS;         // NT
    float* ds_u2t = dinv_t2t + NTXN;             // NU
    float* dd_u2t = ds_u2t + NUSERS;             // NT
    float* ds_t2u = dd_u2t + NTXN;               // NT
    float* dd_t2u = ds_t2u + NTXN;               // NU
    float* gsum = dd_t2u + NUSERS;               // 64
    // converted fp32 weights
    float* Wembu = gsum + 64;            // 32*64
    float* bembu = Wembu + 32 * HD;      // 64
    float* Wembt = bembu + HD;           // 64*64
    float* bembt = Wembt + HD * HD;      // 64
    float* convWf = bembt + HD;          // 3*4*64*64
    float* convbf = convWf + NLAYER * 4 * HD * HD;  // 3*4*64
    float* W1f = convbf + NLAYER * 4 * HD;          // 64*64
    float* b1f = W1f + HD * HD;                     // 64
    float* W2f = b1f + HD;                          // 64
    float* b2f = W2f + HD;                          // 1
    int* dflag = (int*)(b2f + 1);                   // 1

    // zero the degree block + gsum
    hipMemsetAsync(dinv_u2u, 0, (size_t)(3 * NUSERS + 3 * NTXN + 64) * sizeof(float), stream);

    // ---- dtype detect + weight conversion ----
    detect_dtype<<<1, 256, 0, stream>>>((const unsigned short*)x_user, dflag, 2048);
    cvt_to_f32<<<(32 * HD + 255) / 256, 256, 0, stream>>>(d_in[6], Wembu, 32 * HD, dflag);
    cvt_to_f32<<<1, 256, 0, stream>>>(d_in[7], bembu, HD, dflag);
    cvt_to_f32<<<(HD * HD + 255) / 256, 256, 0, stream>>>(d_in[8], Wembt, HD * HD, dflag);
    cvt_to_f32<<<1, 256, 0, stream>>>(d_in[9], bembt, HD, dflag);
    cvt_to_f32<<<(NLAYER * 4 * HD * HD + 255) / 256, 256, 0, stream>>>(d_in[10], convWf,
                                                                      NLAYER * 4 * HD * HD, dflag);
    cvt_to_f32<<<(NLAYER * 4 * HD + 255) / 256, 256, 0, stream>>>(d_in[11], convbf,
                                                                 NLAYER * 4 * HD, dflag);
    cvt_to_f32<<<(HD * HD + 255) / 256, 256, 0, stream>>>(d_in[12], W1f, HD * HD, dflag);
    cvt_to_f32<<<1, 256, 0, stream>>>(d_in[13], b1f, HD, dflag);
    cvt_to_f32<<<1, 256, 0, stream>>>(d_in[14], W2f, HD, dflag);
    cvt_to_f32<<<1, 256, 0, stream>>>(d_in[15], b2f, 1, dflag);

    // ---- degrees ----
    const int degBlocks = (NEDGE + 255) / 256;
    count_deg<<<degBlocks, 256, 0, stream>>>(ei_u2u + NEDGE, dinv_u2u, NEDGE);
    count_deg<<<degBlocks, 256, 0, stream>>>(ei_t2t + NEDGE, dinv_t2t, NEDGE);
    count_deg<<<degBlocks, 256, 0, stream>>>(ei_u2t, ds_u2t, NEDGE);
    count_deg<<<degBlocks, 256, 0, stream>>>(ei_u2t + NEDGE, dd_u2t, NEDGE);
    count_deg<<<degBlocks, 256, 0, stream>>>(ei_t2u, ds_t2u, NEDGE);
    count_deg<<<degBlocks, 256, 0, stream>>>(ei_t2u + NEDGE, dd_t2u, NEDGE);

    finalize_dinv_selfloop<<<(NUSERS + 255) / 256, 256, 0, stream>>>(dinv_u2u, NUSERS);
    finalize_dinv_selfloop<<<(NTXN + 255) / 256, 256, 0, stream>>>(dinv_t2t, NTXN);
    finalize_dinv<<<(NUSERS + 255) / 256, 256, 0, stream>>>(ds_u2t, NUSERS);
    finalize_dinv<<<(NTXN + 255) / 256, 256, 0, stream>>>(dd_u2t, NTXN);
    finalize_dinv<<<(NTXN + 255) / 256, 256, 0, stream>>>(ds_t2u, NTXN);
    finalize_dinv<<<(NUSERS + 255) / 256, 256, 0, stream>>>(dd_t2u, NUSERS);

    // ---- embeddings ----
    const int gU = ((NUSERS + 3) / 4 < 8192) ? (NUSERS + 3) / 4 : 8192;
    const int gT = ((NTXN + 3) / 4 < 8192) ? (NTXN + 3) / 4 : 8192;
    gemm_embed<32><<<gU, 256, 0, stream>>>(x_user, Wembu, bembu, hu, NUSERS, dflag);
    gemm_embed<64><<<gT, 256, 0, stream>>>(x_txn, Wembt, bembt, ht, NTXN, dflag);

    const int scatBlocks = (NEDGE + 3) / 4;

    for (int l = 0; l < NLAYER; ++l) {
        const float* W0   = convWf + ((size_t)l * 4 + 0) * HD * HD;  // u2u
        const float* Wt   = convWf + ((size_t)l * 4 + 1) * HD * HD;  // t2t
        const float* Wu2t = convWf + ((size_t)l * 4 + 2) * HD * HD;
        const float* Wt2u = convWf + ((size_t)l * 4 + 3) * HD * HD;
        const float* B0   = convbf + ((size_t)l * 4 + 0) * HD;
        const float* Bt   = convbf + ((size_t)l * 4 + 1) * HD;
        const float* Bu2t = convbf + ((size_t)l * 4 + 2) * HD;
        const float* Bt2u = convbf + ((size_t)l * 4 + 3) * HD;

        init_acc<<<(NUSERS * HD + 255) / 256, 256, 0, stream>>>(accU, B0, Bt2u, NUSERS * HD);
        init_acc<<<(NTXN * HD + 255) / 256, 256, 0, stream>>>(accT, Bt, Bu2t, NTXN * HD);

        // u2u: hu @ W0 -> accU (+self loops)
        gemm_f32<<<gU, 256, 0, stream>>>(hu, W0, mbuf, NUSERS);
        scatter_edges<<<scatBlocks, 256, 0, stream>>>(mbuf, ei_u2u, ei_u2u + NEDGE,
                                                      dinv_u2u, dinv_u2u, accU, NEDGE);
        selfloop_add<<<(NUSERS + 3) / 4, 256, 0, stream>>>(mbuf, dinv_u2u, accU, NUSERS);

        // u2t: hu @ Wu2t -> accT
        gemm_f32<<<gU, 256, 0, stream>>>(hu, Wu2t, mbuf, NUSERS);
        scatter_edges<<<scatBlocks, 256, 0, stream>>>(mbuf, ei_u2t, ei_u2t + NEDGE,
                                                      ds_u2t, dd_u2t, accT, NEDGE);

        // t2t: ht @ Wt -> accT (+self loops)
        gemm_f32<<<gT, 256, 0, stream>>>(ht, Wt, mbuf, NTXN);
        scatter_edges<<<scatBlocks, 256, 0, stream>>>(mbuf, ei_t2t, ei_t2t + NEDGE,
                                                      dinv_t2t, dinv_t2t, accT, NEDGE);
        selfloop_add<<<(NTXN + 3) / 4, 256, 0, stream>>>(mbuf, dinv_t2t, accT, NTXN);

        // t2u: ht @ Wt2u -> accU
        gemm_f32<<<gT, 256, 0, stream>>>(ht, Wt2u, mbuf, NTXN);
        scatter_edges<<<scatBlocks, 256, 0, stream>>>(mbuf, ei_t2u, ei_t2u + NEDGE,
                                                      ds_t2u, dd_t2u, accU, NEDGE);

        relu_half<<<(NUSERS * HD + 255) / 256, 256, 0, stream>>>(accU, hu, NUSERS * HD);
        relu_half<<<(NTXN * HD + 255) / 256, 256, 0, stream>>>(accT, ht, NTXN * HD);
    }

    // ---- readout ----
    colmean<<<512, 256, 0, stream>>>(hu, NUSERS, 0.5f / NUSERS, gsum);
    colmean<<<512, 256, 0, stream>>>(ht, NTXN, 0.5f / NTXN, gsum);
    head<<<1, 64, 0, stream>>>(gsum, W1f, b1f, W2f, b2f, dflag, d_out);
}

// Round 3
// 3198.126 us; speedup vs baseline: 1.4995x; 1.4995x over previous
//
#include <hip/hip_runtime.h>
#include <hip/hip_bf16.h>

#define NU_ 100000
#define NT_ 200000
#define NE_ 1000000
#define HD  64
#define NL  3

// hist/dinv region offsets (node-keyed arrays)
#define OFF0 0                   // u2u dst (NU)  [selfloop]
#define OFF1 (NU_)               // t2t dst (NT)  [selfloop]
#define OFF2 (NU_ + NT_)         // u2t dst (NT)
#define OFF3 (NU_ + 2 * NT_)     // t2u dst (NU)
#define OFF4 (2 * NU_ + 2 * NT_) // u2t src (NU)
#define OFF5 (3 * NU_ + 2 * NT_) // t2u src (NT)
#define HTOT (3 * NU_ + 3 * NT_) // 900k
#define RPTOT (2 * NU_ + 2 * NT_) // 600k (first 4 regions)

// scan block partition (256/block)
#define NB0 391   // ceil(NU/256)
#define NB1 782   // ceil(NT/256)
#define CB1 391
#define CB2 1173
#define CB3 1955
#define NBTOT 2346

// ---------------- dtype detection ----------------
__global__ void detect_dtype(const unsigned short* __restrict__ x, int* __restrict__ flag, int n) {
    __shared__ int s_big;
    if (threadIdx.x == 0) s_big = 0;
    __syncthreads();
    int big = 0;
    for (int i = threadIdx.x; i < n; i += blockDim.x) {
        float v = __uint_as_float(((unsigned int)x[i]) << 16);
        if (!(fabsf(v) < 1.0e4f)) big = 1;
    }
    if (big) atomicAdd(&s_big, 1);
    __syncthreads();
    if (threadIdx.x == 0) flag[0] = (s_big > 0) ? 0 : 1;
}

// ---------------- fused weight conversion (+ gsum zero) ----------------
struct Ptr10 { const void* p[10]; };

__global__ void cvt_weights(Ptr10 src, float* __restrict__ dst, float* __restrict__ gsum,
                            const int* __restrict__ flag) {
    const int c[11] = {0, 2048, 2112, 6208, 6272, 55424, 56192, 60288, 60352, 60416, 60417};
    int i = blockIdx.x * blockDim.x + threadIdx.x;
    if (i < 64) gsum[i] = 0.f;
    if (i >= 60417) return;
    int r = 0;
#pragma unroll
    for (int k = 1; k < 10; ++k)
        if (i >= c[k]) r = k;
    int e = i - c[r];
    if (flag[0]) {
        unsigned short u = ((const unsigned short*)src.p[r])[e];
        dst[i] = __uint_as_float(((unsigned int)u) << 16);
    } else {
        dst[i] = ((const float*)src.p[r])[e];
    }
}

// ---------------- fused 6-way histogram ----------------
__global__ __launch_bounds__(256) void hist6(const int* __restrict__ a0, const int* __restrict__ a1,
                                             const int* __restrict__ a2, const int* __restrict__ a3,
                                             const int* __restrict__ a4, const int* __restrict__ a5,
                                             int* __restrict__ hist) {
    int gid = blockIdx.x * 256 + threadIdx.x;
    if (gid >= 6 * NE_) return;
    int r = gid / NE_;
    int e = gid - r * NE_;
    const int* a;
    int base;
    switch (r) {
        case 0: a = a0; base = OFF0; break;
        case 1: a = a1; base = OFF1; break;
        case 2: a = a2; base = OFF2; break;
        case 3: a = a3; base = OFF3; break;
        case 4: a = a4; base = OFF4; break;
        default: a = a5; base = OFF5; break;
    }
    atomicAdd(&hist[base + a[e]], 1);
}

// ---------------- dinv from histograms ----------------
__global__ void dinv_all(const int* __restrict__ hist, float* __restrict__ dinv) {
    int i = blockIdx.x * blockDim.x + threadIdx.x;
    if (i >= HTOT) return;
    int h = hist[i];
    float v;
    if (i < OFF2) v = rsqrtf((float)h + 1.0f);              // self-loop types
    else v = (h > 0) ? rsqrtf((float)h) : 0.f;              // bipartite
    dinv[i] = v;
}

// ---------------- scan stage 1: per-block exclusive scan ----------------
__global__ __launch_bounds__(256) void scan1(const int* __restrict__ hist, int* __restrict__ rp,
                                             int* __restrict__ bsums) {
    int b = blockIdx.x, t = threadIdx.x;
    int r, lb, base, n;
    if (b < CB1)      { r = 0; lb = b;       base = OFF0; n = NU_; }
    else if (b < CB2) { r = 1; lb = b - CB1; base = OFF1; n = NT_; }
    else if (b < CB3) { r = 2; lb = b - CB2; base = OFF2; n = NT_; }
    else              { r = 3; lb = b - CB3; base = OFF3; n = NU_; }
    int i = lb * 256 + t;
    int v = (i < n) ? hist[base + i] : 0;
    __shared__ int s[256];
    s[t] = v;
    __syncthreads();
    for (int off = 1; off < 256; off <<= 1) {
        int x = (t >= off) ? s[t - off] : 0;
        __syncthreads();
        s[t] += x;
        __syncthreads();
    }
    if (i < n) rp[base + i] = s[t] - v;
    if (t == 255) bsums[r * 1024 + lb] = s[255];
}

// ---------------- scan stage 2: scan block sums (4 blocks) ----------------
__global__ __launch_bounds__(1024) void scan2(int* __restrict__ bsums) {
    int r = blockIdx.x, t = threadIdx.x;
    const int nb = (r == 0 || r == 3) ? NB0 : NB1;
    int v = (t < nb) ? bsums[r * 1024 + t] : 0;
    __shared__ int s[1024];
    s[t] = v;
    __syncthreads();
    for (int off = 1; off < 1024; off <<= 1) {
        int x = (t >= off) ? s[t - off] : 0;
        __syncthreads();
        s[t] += x;
        __syncthreads();
    }
    if (t < nb) bsums[r * 1024 + t] = s[t] - v;  // exclusive
}

// ---------------- scan stage 3: add block offsets ----------------
__global__ void scan3(int* __restrict__ rp, const int* __restrict__ bsums) {
    int gid = blockIdx.x * blockDim.x + threadIdx.x;
    if (gid >= RPTOT) return;
    int r, base;
    if (gid < OFF1)      { r = 0; base = OFF0; }
    else if (gid < OFF2) { r = 1; base = OFF1; }
    else if (gid < OFF3) { r = 2; base = OFF2; }
    else                 { r = 3; base = OFF3; }
    int lb = (gid - base) >> 8;
    rp[gid] += bsums[r * 1024 + lb];
}

// ---------------- CSR placement ----------------
__global__ __launch_bounds__(256) void place4(const int* __restrict__ e0, const int* __restrict__ e1,
                                              const int* __restrict__ e2, const int* __restrict__ e3,
                                              const int* __restrict__ rp, int* __restrict__ fill,
                                              int* __restrict__ col) {
    int gid = blockIdx.x * 256 + threadIdx.x;
    if (gid >= 4 * NE_) return;
    int r = gid / NE_;
    int e = gid - r * NE_;
    const int* ei;
    int base;
    switch (r) {
        case 0: ei = e0; base = OFF0; break;
        case 1: ei = e1; base = OFF1; break;
        case 2: ei = e2; base = OFF2; break;
        default: ei = e3; base = OFF3; break;
    }
    int s = ei[e];
    int d = ei[e + NE_];
    int pos = rp[base + d] + atomicAdd(&fill[base + d], 1);
    col[r * NE_ + pos] = s;
}

// ---------------- embedding GEMM (runtime dtype) ----------------
template <int K>
__global__ __launch_bounds__(256) void gemm_embed(const void* __restrict__ x,
                                                  const float* __restrict__ W,
                                                  const float* __restrict__ bias,
                                                  float* __restrict__ out, int N,
                                                  const int* __restrict__ flag) {
    const int lane = threadIdx.x & 63;
    float w[K];
#pragma unroll
    for (int k = 0; k < K; ++k) w[k] = W[k * HD + lane];
    const float b = bias[lane];
    const bool isb = flag[0] != 0;
    const int wid = (blockIdx.x << 2) + (threadIdx.x >> 6);
    const int stride = gridDim.x << 2;
    if (isb) {
        const unsigned short* xb = (const unsigned short*)x;
        for (int r = wid; r < N; r += stride) {
            const unsigned short* xr = xb + (size_t)r * K;
            float acc = b;
#pragma unroll
            for (int k = 0; k < K; ++k)
                acc = fmaf(__uint_as_float(((unsigned int)xr[k]) << 16), w[k], acc);
            out[(size_t)r * HD + lane] = acc;
        }
    } else {
        const float* xf = (const float*)x;
        for (int r = wid; r < N; r += stride) {
            const float* xr = xf + (size_t)r * K;
            float acc = b;
#pragma unroll
            for (int k = 0; k < K; ++k) acc = fmaf(xr[k], w[k], acc);
            out[(size_t)r * HD + lane] = acc;
        }
    }
}

// ---------------- layer GEMM with src-dinv scaling: m = (h @ W) * sc[r] ------
__global__ __launch_bounds__(256) void gemm_scaled(const float* __restrict__ h,
                                                   const float* __restrict__ W,
                                                   const float* __restrict__ sc,
                                                   float* __restrict__ out, int N) {
    const int lane = threadIdx.x & 63;
    float w[HD];
#pragma unroll
    for (int k = 0; k < HD; ++k) w[k] = W[k * HD + lane];
    const int wid = (blockIdx.x << 2) + (threadIdx.x >> 6);
    const int stride = gridDim.x << 2;
    for (int r = wid; r < N; r += stride) {
        const float* hr = h + (size_t)r * HD;
        float acc = 0.f;
#pragma unroll
        for (int k = 0; k < HD; ++k) acc = fmaf(hr[k], w[k], acc);
        out[(size_t)r * HD + lane] = acc * sc[r];
    }
}

// ---------------- fused dual-relation gather + self-loop + bias + relu -------
// out[d] = relu(0.5*( dA[d]*(m_A[d] + sum_{j in A(d)} m_A[colA[j]])
//                   + dB[d]*(        sum_{j in B(d)} m_B[colB[j]])
//                   + ba + bb ))
__global__ __launch_bounds__(256) void gather2(const float* __restrict__ mA,
                                               const float* __restrict__ mB,
                                               const int* __restrict__ rpA,
                                               const int* __restrict__ cntA,
                                               const int* __restrict__ colA,
                                               const float* __restrict__ dA,
                                               const int* __restrict__ rpB,
                                               const int* __restrict__ cntB,
                                               const int* __restrict__ colB,
                                               const float* __restrict__ dB,
                                               const float* __restrict__ ba,
                                               const float* __restrict__ bb,
                                               float* __restrict__ out, int N) {
    const int lane = threadIdx.x & 63;
    const int d = (blockIdx.x << 2) + (threadIdx.x >> 6);
    if (d >= N) return;
    float s0 = mA[(size_t)d * HD + lane];  // self-loop term (pre-scaled by dinv[src=d])
    {
        int st = rpA[d], en = st + cntA[d];
        for (int j = st; j < en; ++j) s0 += mA[(size_t)colA[j] * HD + lane];
    }
    float s1 = 0.f;
    {
        int st = rpB[d], en = st + cntB[d];
        for (int j = st; j < en; ++j) s1 += mB[(size_t)colB[j] * HD + lane];
    }
    float v = 0.5f * (dA[d] * s0 + dB[d] * s1 + ba[lane] + bb[lane]);
    out[(size_t)d * HD + lane] = fmaxf(v, 0.f);
}

// ---------------- column mean (scaled) into gsum[64] ----------------
__global__ __launch_bounds__(256) void colmean(const float* __restrict__ h, int n, float scale,
                                               float* __restrict__ gsum) {
    const int lane = threadIdx.x & 63;
    const int w = threadIdx.x >> 6;
    float s = 0.f;
    for (int r = blockIdx.x * 4 + w; r < n; r += gridDim.x * 4)
        s += h[(size_t)r * HD + lane];
    __shared__ float red[256];
    red[threadIdx.x] = s;
    __syncthreads();
    if (threadIdx.x < 64) {
        float t = red[threadIdx.x] + red[64 + threadIdx.x] + red[128 + threadIdx.x] +
                  red[192 + threadIdx.x];
        atomicAdd(&gsum[lane], t * scale);
    }
}

// ---------------- head MLP ----------------
__global__ void head(const float* __restrict__ g, const float* __restrict__ W1,
                     const float* __restrict__ b1, const float* __restrict__ W2,
                     const float* __restrict__ b2, const int* __restrict__ flag,
                     void* __restrict__ out) {
    const int c = threadIdx.x;  // one wave
    float x = b1[c];
    for (int k = 0; k < HD; ++k) x = fmaf(g[k], W1[k * HD + c], x);
    x = fmaxf(x, 0.f);
    float t = x * W2[c];
    for (int off = 32; off; off >>= 1) t += __shfl_down(t, off);
    if (c == 0) {
        float z = t + b2[0];
        float s = 1.f / (1.f + expf(-z));
        if (flag[0]) *(__hip_bfloat16*)out = __float2bfloat16(s);
        else *(float*)out = s;
    }
}

extern "C" void kernel_launch(void* const* d_in, const int* in_sizes, int n_in,
                              void* d_out, int out_size, void* d_ws, size_t ws_size,
                              hipStream_t stream) {
    const void* x_user = d_in[0];
    const void* x_txn  = d_in[1];
    const int* ei_u2u = (const int*)d_in[2];
    const int* ei_t2t = (const int*)d_in[3];
    const int* ei_u2t = (const int*)d_in[4];
    const int* ei_t2u = (const int*)d_in[5];

    // ---- workspace layout ----
    float* ws = (float*)d_ws;
    float* hu   = ws;                               // NU*64
    float* ht   = hu + (size_t)NU_ * HD;            // NT*64
    float* pool = ht + (size_t)NT_ * HD;            // (NT+2NU)*64
    float* m_tu = pool;                             // NT*64 (also m_tt slot)
    float* m_uu = pool + (size_t)NT_ * HD;          // NU*64
    float* m_ut = m_uu + (size_t)NU_ * HD;          // NU*64
    float* dinv = m_ut + (size_t)NU_ * HD;          // HTOT
    float* wts  = dinv + HTOT;                      // 60417
    float* gsum = wts + 60417;                      // 64
    int* hist = (int*)(gsum + 64);                  // HTOT (900k)
    int* fill = hist + HTOT;                        // RPTOT (600k)
    int* rp   = fill + RPTOT;                       // RPTOT (600k)
    int* bsums = rp + RPTOT;                        // 4096
    int* col  = bsums + 4096;                       // 4*NE
    int* dflag = col + 4 * NE_;                     // 1

    // fp32 weight sub-pointers (order matches cvt regions)
    float* Wembu = wts;              // 2048
    float* bembu = Wembu + 2048;     // 64
    float* Wembt = bembu + 64;       // 4096
    float* bembt = Wembt + 4096;     // 64
    float* convWf = bembt + 64;      // 49152
    float* convbf = convWf + 49152;  // 768
    float* W1f = convbf + 768;       // 4096
    float* b1f = W1f + 4096;         // 64
    float* W2f = b1f + 64;           // 64
    float* b2f = W2f + 64;           // 1

    // zero hist + fill (contiguous)
    hipMemsetAsync(hist, 0, (size_t)(HTOT + RPTOT) * sizeof(int), stream);

    detect_dtype<<<1, 256, 0, stream>>>((const unsigned short*)x_user, dflag, 2048);
    {
        Ptr10 p;
        for (int k = 0; k < 10; ++k) p.p[k] = d_in[6 + k];
        cvt_weights<<<(60417 + 255) / 256, 256, 0, stream>>>(p, wts, gsum, dflag);
    }

    // ---- histograms, dinv, CSR ----
    hist6<<<(6 * NE_ + 255) / 256, 256, 0, stream>>>(ei_u2u + NE_, ei_t2t + NE_, ei_u2t + NE_,
                                                     ei_t2u + NE_, ei_u2t, ei_t2u, hist);
    dinv_all<<<(HTOT + 255) / 256, 256, 0, stream>>>(hist, dinv);
    scan1<<<NBTOT, 256, 0, stream>>>(hist, rp, bsums);
    scan2<<<4, 1024, 0, stream>>>(bsums);
    scan3<<<(RPTOT + 255) / 256, 256, 0, stream>>>(rp, bsums);
    place4<<<(4 * NE_ + 255) / 256, 256, 0, stream>>>(ei_u2u, ei_t2t, ei_u2t, ei_t2u,
                                                      rp, fill, col);

    // ---- embeddings ----
    gemm_embed<32><<<8192, 256, 0, stream>>>(x_user, Wembu, bembu, hu, NU_, dflag);
    gemm_embed<64><<<8192, 256, 0, stream>>>(x_txn, Wembt, bembt, ht, NT_, dflag);

    const int gbU = (NU_ + 3) / 4;
    const int gbT = (NT_ + 3) / 4;

    for (int l = 0; l < NL; ++l) {
        const float* W0   = convWf + ((size_t)l * 4 + 0) * HD * HD;
        const float* Wt   = convWf + ((size_t)l * 4 + 1) * HD * HD;
        const float* Wu2t = convWf + ((size_t)l * 4 + 2) * HD * HD;
        const float* Wt2u = convWf + ((size_t)l * 4 + 3) * HD * HD;
        const float* B0   = convbf + ((size_t)l * 4 + 0) * HD;
        const float* Bt   = convbf + ((size_t)l * 4 + 1) * HD;
        const float* Bu2t = convbf + ((size_t)l * 4 + 2) * HD;
        const float* Bt2u = convbf + ((size_t)l * 4 + 3) * HD;

        // GEMMs that consume old hu/ht (m pre-scaled by dinv[src])
        gemm_scaled<<<8192, 256, 0, stream>>>(hu, W0,   dinv + OFF0, m_uu, NU_);
        gemm_scaled<<<8192, 256, 0, stream>>>(hu, Wu2t, dinv + OFF4, m_ut, NU_);
        gemm_scaled<<<8192, 256, 0, stream>>>(ht, Wt2u, dinv + OFF5, m_tu, NT_);

        // user update: u2u (self-loop) + t2u, overwrites hu in place
        gather2<<<gbU, 256, 0, stream>>>(m_uu, m_tu,
                                         rp + OFF0, hist + OFF0, col + 0 * NE_, dinv + OFF0,
                                         rp + OFF3, hist + OFF3, col + 3 * NE_, dinv + OFF3,
                                         B0, Bt2u, hu, NU_);

        // t2t GEMM reuses m_tu slot (m_tu consumed above)
        gemm_scaled<<<8192, 256, 0, stream>>>(ht, Wt, dinv + OFF1, m_tu, NT_);

        // txn update: t2t (self-loop) + u2t, overwrites ht in place
        gather2<<<gbT, 256, 0, stream>>>(m_tu, m_ut,
                                         rp + OFF1, hist + OFF1, col + 1 * NE_, dinv + OFF1,
                                         rp + OFF2, hist + OFF2, col + 2 * NE_, dinv + OFF2,
                                         Bt, Bu2t, ht, NT_);
    }

    // ---- readout ----
    colmean<<<512, 256, 0, stream>>>(hu, NU_, 0.5f / NU_, gsum);
    colmean<<<512, 256, 0, stream>>>(ht, NT_, 0.5f / NT_, gsum);
    head<<<1, 64, 0, stream>>>(gsum, W1f, b1f, W2f, b2f, dflag, d_out);
}

// Round 4
// 2405.453 us; speedup vs baseline: 1.9936x; 1.3295x over previous
//
#include <hip/hip_runtime.h>
#include <hip/hip_bf16.h>

#define NU_ 100000
#define NT_ 200000
#define NE_ 1000000
#define HD  64
#define NL  3

// hist/dinv region offsets (node-keyed arrays)
#define OFF0 0                   // u2u dst (NU)  [selfloop]
#define OFF1 (NU_)               // t2t dst (NT)  [selfloop]
#define OFF2 (NU_ + NT_)         // u2t dst (NT)
#define OFF3 (NU_ + 2 * NT_)     // t2u dst (NU)
#define OFF4 (2 * NU_ + 2 * NT_) // u2t src (NU)
#define OFF5 (3 * NU_ + 2 * NT_) // t2u src (NT)
#define HTOT (3 * NU_ + 3 * NT_) // 900k
#define RPTOT (2 * NU_ + 2 * NT_) // 600k (first 4 regions)

// scan block partition (256/block)
#define NB0 391   // ceil(NU/256)
#define NB1 782   // ceil(NT/256)
#define CB1 391
#define CB2 1173
#define CB3 1955
#define NBTOT 2346

// ---------------- dtype detection ----------------
__global__ void detect_dtype(const unsigned short* __restrict__ x, int* __restrict__ flag, int n) {
    __shared__ int s_big;
    if (threadIdx.x == 0) s_big = 0;
    __syncthreads();
    int big = 0;
    for (int i = threadIdx.x; i < n; i += blockDim.x) {
        float v = __uint_as_float(((unsigned int)x[i]) << 16);
        if (!(fabsf(v) < 1.0e4f)) big = 1;
    }
    if (big) atomicAdd(&s_big, 1);
    __syncthreads();
    if (threadIdx.x == 0) flag[0] = (s_big > 0) ? 0 : 1;
}

// ---------------- fused weight conversion (+ gsum zero) ----------------
struct Ptr10 { const void* p[10]; };

__global__ void cvt_weights(Ptr10 src, float* __restrict__ dst, float* __restrict__ gsum,
                            const int* __restrict__ flag) {
    const int c[11] = {0, 2048, 2112, 6208, 6272, 55424, 56192, 60288, 60352, 60416, 60417};
    int i = blockIdx.x * blockDim.x + threadIdx.x;
    if (i < 64) gsum[i] = 0.f;
    if (i >= 60417) return;
    int r = 0;
#pragma unroll
    for (int k = 1; k < 10; ++k)
        if (i >= c[k]) r = k;
    int e = i - c[r];
    if (flag[0]) {
        unsigned short u = ((const unsigned short*)src.p[r])[e];
        dst[i] = __uint_as_float(((unsigned int)u) << 16);
    } else {
        dst[i] = ((const float*)src.p[r])[e];
    }
}

// ---------------- fused 6-way histogram ----------------
__global__ __launch_bounds__(256) void hist6(const int* __restrict__ a0, const int* __restrict__ a1,
                                             const int* __restrict__ a2, const int* __restrict__ a3,
                                             const int* __restrict__ a4, const int* __restrict__ a5,
                                             int* __restrict__ hist) {
    int gid = blockIdx.x * 256 + threadIdx.x;
    if (gid >= 6 * NE_) return;
    int r = gid / NE_;
    int e = gid - r * NE_;
    const int* a;
    int base;
    switch (r) {
        case 0: a = a0; base = OFF0; break;
        case 1: a = a1; base = OFF1; break;
        case 2: a = a2; base = OFF2; break;
        case 3: a = a3; base = OFF3; break;
        case 4: a = a4; base = OFF4; break;
        default: a = a5; base = OFF5; break;
    }
    atomicAdd(&hist[base + a[e]], 1);
}

// ---------------- dinv from histograms ----------------
__global__ void dinv_all(const int* __restrict__ hist, float* __restrict__ dinv) {
    int i = blockIdx.x * blockDim.x + threadIdx.x;
    if (i >= HTOT) return;
    int h = hist[i];
    float v;
    if (i < OFF2) v = rsqrtf((float)h + 1.0f);
    else v = (h > 0) ? rsqrtf((float)h) : 0.f;
    dinv[i] = v;
}

// ---------------- scan stage 1 ----------------
__global__ __launch_bounds__(256) void scan1(const int* __restrict__ hist, int* __restrict__ rp,
                                             int* __restrict__ bsums) {
    int b = blockIdx.x, t = threadIdx.x;
    int r, lb, base, n;
    if (b < CB1)      { r = 0; lb = b;       base = OFF0; n = NU_; }
    else if (b < CB2) { r = 1; lb = b - CB1; base = OFF1; n = NT_; }
    else if (b < CB3) { r = 2; lb = b - CB2; base = OFF2; n = NT_; }
    else              { r = 3; lb = b - CB3; base = OFF3; n = NU_; }
    int i = lb * 256 + t;
    int v = (i < n) ? hist[base + i] : 0;
    __shared__ int s[256];
    s[t] = v;
    __syncthreads();
    for (int off = 1; off < 256; off <<= 1) {
        int x = (t >= off) ? s[t - off] : 0;
        __syncthreads();
        s[t] += x;
        __syncthreads();
    }
    if (i < n) rp[base + i] = s[t] - v;
    if (t == 255) bsums[r * 1024 + lb] = s[255];
}

// ---------------- scan stage 2 ----------------
__global__ __launch_bounds__(1024) void scan2(int* __restrict__ bsums) {
    int r = blockIdx.x, t = threadIdx.x;
    const int nb = (r == 0 || r == 3) ? NB0 : NB1;
    int v = (t < nb) ? bsums[r * 1024 + t] : 0;
    __shared__ int s[1024];
    s[t] = v;
    __syncthreads();
    for (int off = 1; off < 1024; off <<= 1) {
        int x = (t >= off) ? s[t - off] : 0;
        __syncthreads();
        s[t] += x;
        __syncthreads();
    }
    if (t < nb) bsums[r * 1024 + t] = s[t] - v;
}

// ---------------- scan stage 3 ----------------
__global__ void scan3(int* __restrict__ rp, const int* __restrict__ bsums) {
    int gid = blockIdx.x * blockDim.x + threadIdx.x;
    if (gid >= RPTOT) return;
    int r, base;
    if (gid < OFF1)      { r = 0; base = OFF0; }
    else if (gid < OFF2) { r = 1; base = OFF1; }
    else if (gid < OFF3) { r = 2; base = OFF2; }
    else                 { r = 3; base = OFF3; }
    int lb = (gid - base) >> 8;
    rp[gid] += bsums[r * 1024 + lb];
}

// ---------------- CSR placement ----------------
__global__ __launch_bounds__(256) void place4(const int* __restrict__ e0, const int* __restrict__ e1,
                                              const int* __restrict__ e2, const int* __restrict__ e3,
                                              const int* __restrict__ rp, int* __restrict__ fill,
                                              int* __restrict__ col) {
    int gid = blockIdx.x * 256 + threadIdx.x;
    if (gid >= 4 * NE_) return;
    int r = gid / NE_;
    int e = gid - r * NE_;
    const int* ei;
    int base;
    switch (r) {
        case 0: ei = e0; base = OFF0; break;
        case 1: ei = e1; base = OFF1; break;
        case 2: ei = e2; base = OFF2; break;
        default: ei = e3; base = OFF3; break;
    }
    int s = ei[e];
    int d = ei[e + NE_];
    int pos = rp[base + d] + atomicAdd(&fill[base + d], 1);
    col[r * NE_ + pos] = s;
}

// ---------------- embedding GEMM (runtime dtype) ----------------
template <int K>
__global__ __launch_bounds__(256) void gemm_embed(const void* __restrict__ x,
                                                  const float* __restrict__ W,
                                                  const float* __restrict__ bias,
                                                  float* __restrict__ out, int N,
                                                  const int* __restrict__ flag) {
    const int lane = threadIdx.x & 63;
    float w[K];
#pragma unroll
    for (int k = 0; k < K; ++k) w[k] = W[k * HD + lane];
    const float b = bias[lane];
    const bool isb = flag[0] != 0;
    const int wid = (blockIdx.x << 2) + (threadIdx.x >> 6);
    const int stride = gridDim.x << 2;
    if (isb) {
        const unsigned short* xb = (const unsigned short*)x;
        for (int r = wid; r < N; r += stride) {
            const unsigned short* xr = xb + (size_t)r * K;
            float acc = b;
#pragma unroll
            for (int k = 0; k < K; ++k)
                acc = fmaf(__uint_as_float(((unsigned int)xr[k]) << 16), w[k], acc);
            out[(size_t)r * HD + lane] = acc;
        }
    } else {
        const float* xf = (const float*)x;
        for (int r = wid; r < N; r += stride) {
            const float* xr = xf + (size_t)r * K;
            float acc = b;
#pragma unroll
            for (int k = 0; k < K; ++k) acc = fmaf(xr[k], w[k], acc);
            out[(size_t)r * HD + lane] = acc;
        }
    }
}

// ---------------- dual-output GEMM: mA = (h@WA)*scA, mB = (h@WB)*scB (bf16 out)
// One coalesced row load; broadcast via shfl; 128 FMAs per load.
__global__ __launch_bounds__(256) void gemm_dual(const float* __restrict__ h,
                                                 const float* __restrict__ WA,
                                                 const float* __restrict__ WB,
                                                 const float* __restrict__ scA,
                                                 const float* __restrict__ scB,
                                                 __hip_bfloat16* __restrict__ mA,
                                                 __hip_bfloat16* __restrict__ mB, int N) {
    const int lane = threadIdx.x & 63;
    float wa[HD], wb[HD];
#pragma unroll
    for (int k = 0; k < HD; ++k) wa[k] = WA[k * HD + lane];
#pragma unroll
    for (int k = 0; k < HD; ++k) wb[k] = WB[k * HD + lane];
    const int wid = (blockIdx.x << 2) + (threadIdx.x >> 6);
    const int stride = gridDim.x << 2;
    for (int r = wid; r < N; r += stride) {
        const float hv = h[(size_t)r * HD + lane];
        float accA = 0.f, accB = 0.f;
#pragma unroll
        for (int k = 0; k < HD; ++k) {
            float hk = __shfl(hv, k);
            accA = fmaf(hk, wa[k], accA);
            accB = fmaf(hk, wb[k], accB);
        }
        mA[(size_t)r * HD + lane] = __float2bfloat16(accA * scA[r]);
        mB[(size_t)r * HD + lane] = __float2bfloat16(accB * scB[r]);
    }
}

// ---------------- fused dual-relation gather (bf16 m) + selfloop + bias + relu
__global__ __launch_bounds__(256) void gather2(const __hip_bfloat16* __restrict__ mA,
                                               const __hip_bfloat16* __restrict__ mB,
                                               const int* __restrict__ rpA,
                                               const int* __restrict__ cntA,
                                               const int* __restrict__ colA,
                                               const float* __restrict__ dA,
                                               const int* __restrict__ rpB,
                                               const int* __restrict__ cntB,
                                               const int* __restrict__ colB,
                                               const float* __restrict__ dB,
                                               const float* __restrict__ ba,
                                               const float* __restrict__ bb,
                                               float* __restrict__ out, int N) {
    const int lane = threadIdx.x & 63;
    const int d = (blockIdx.x << 2) + (threadIdx.x >> 6);
    if (d >= N) return;
    float a0 = __bfloat162float(mA[(size_t)d * HD + lane]);  // self-loop (pre-scaled by src dinv)
    float a1 = 0.f, b0 = 0.f, b1 = 0.f;
    {
        int j = rpA[d], en = j + cntA[d];
        for (; j + 1 < en; j += 2) {
            int c0 = colA[j], c1 = colA[j + 1];
            a0 += __bfloat162float(mA[(size_t)c0 * HD + lane]);
            a1 += __bfloat162float(mA[(size_t)c1 * HD + lane]);
        }
        if (j < en) a0 += __bfloat162float(mA[(size_t)colA[j] * HD + lane]);
    }
    {
        int j = rpB[d], en = j + cntB[d];
        for (; j + 1 < en; j += 2) {
            int c0 = colB[j], c1 = colB[j + 1];
            b0 += __bfloat162float(mB[(size_t)c0 * HD + lane]);
            b1 += __bfloat162float(mB[(size_t)c1 * HD + lane]);
        }
        if (j < en) b0 += __bfloat162float(mB[(size_t)colB[j] * HD + lane]);
    }
    float v = 0.5f * (dA[d] * (a0 + a1) + dB[d] * (b0 + b1) + ba[lane] + bb[lane]);
    out[(size_t)d * HD + lane] = fmaxf(v, 0.f);
}

// ---------------- column mean (scaled) into gsum[64] ----------------
__global__ __launch_bounds__(256) void colmean(const float* __restrict__ h, int n, float scale,
                                               float* __restrict__ gsum) {
    const int lane = threadIdx.x & 63;
    const int w = threadIdx.x >> 6;
    float s = 0.f;
    for (int r = blockIdx.x * 4 + w; r < n; r += gridDim.x * 4)
        s += h[(size_t)r * HD + lane];
    __shared__ float red[256];
    red[threadIdx.x] = s;
    __syncthreads();
    if (threadIdx.x < 64) {
        float t = red[threadIdx.x] + red[64 + threadIdx.x] + red[128 + threadIdx.x] +
                  red[192 + threadIdx.x];
        atomicAdd(&gsum[lane], t * scale);
    }
}

// ---------------- head MLP ----------------
__global__ void head(const float* __restrict__ g, const float* __restrict__ W1,
                     const float* __restrict__ b1, const float* __restrict__ W2,
                     const float* __restrict__ b2, const int* __restrict__ flag,
                     void* __restrict__ out) {
    const int c = threadIdx.x;
    float x = b1[c];
    for (int k = 0; k < HD; ++k) x = fmaf(g[k], W1[k * HD + c], x);
    x = fmaxf(x, 0.f);
    float t = x * W2[c];
    for (int off = 32; off; off >>= 1) t += __shfl_down(t, off);
    if (c == 0) {
        float z = t + b2[0];
        float s = 1.f / (1.f + expf(-z));
        if (flag[0]) *(__hip_bfloat16*)out = __float2bfloat16(s);
        else *(float*)out = s;
    }
}

extern "C" void kernel_launch(void* const* d_in, const int* in_sizes, int n_in,
                              void* d_out, int out_size, void* d_ws, size_t ws_size,
                              hipStream_t stream) {
    const void* x_user = d_in[0];
    const void* x_txn  = d_in[1];
    const int* ei_u2u = (const int*)d_in[2];
    const int* ei_t2t = (const int*)d_in[3];
    const int* ei_u2t = (const int*)d_in[4];
    const int* ei_t2u = (const int*)d_in[5];

    // ---- workspace layout ----
    float* ws = (float*)d_ws;
    float* hu = ws;                                   // NU*64 f32
    float* ht = hu + (size_t)NU_ * HD;                // NT*64 f32
    float* dinv = ht + (size_t)NT_ * HD;              // HTOT
    float* wts = dinv + HTOT;                         // 60417
    float* gsum = wts + 60417;                        // 64
    __hip_bfloat16* m_uu = (__hip_bfloat16*)(gsum + 64);  // NU*64 bf16
    __hip_bfloat16* m_ut = m_uu + (size_t)NU_ * HD;       // NU*64
    __hip_bfloat16* m_tt = m_ut + (size_t)NU_ * HD;       // NT*64
    __hip_bfloat16* m_tu = m_tt + (size_t)NT_ * HD;       // NT*64
    int* hist = (int*)(m_tu + (size_t)NT_ * HD);      // HTOT
    int* fill = hist + HTOT;                          // RPTOT
    int* rp   = fill + RPTOT;                         // RPTOT
    int* bsums = rp + RPTOT;                          // 4096
    int* col  = bsums + 4096;                         // 4*NE
    int* dflag = col + 4 * NE_;                       // 1

    // fp32 weight sub-pointers
    float* Wembu = wts;              // 2048
    float* bembu = Wembu + 2048;     // 64
    float* Wembt = bembu + 64;       // 4096
    float* bembt = Wembt + 4096;     // 64
    float* convWf = bembt + 64;      // 49152
    float* convbf = convWf + 49152;  // 768
    float* W1f = convbf + 768;       // 4096
    float* b1f = W1f + 4096;         // 64
    float* W2f = b1f + 64;           // 64
    float* b2f = W2f + 64;           // 1

    hipMemsetAsync(hist, 0, (size_t)(HTOT + RPTOT) * sizeof(int), stream);

    detect_dtype<<<1, 256, 0, stream>>>((const unsigned short*)x_user, dflag, 2048);
    {
        Ptr10 p;
        for (int k = 0; k < 10; ++k) p.p[k] = d_in[6 + k];
        cvt_weights<<<(60417 + 255) / 256, 256, 0, stream>>>(p, wts, gsum, dflag);
    }

    // ---- histograms, dinv, CSR ----
    hist6<<<(6 * NE_ + 255) / 256, 256, 0, stream>>>(ei_u2u + NE_, ei_t2t + NE_, ei_u2t + NE_,
                                                     ei_t2u + NE_, ei_u2t, ei_t2u, hist);
    dinv_all<<<(HTOT + 255) / 256, 256, 0, stream>>>(hist, dinv);
    scan1<<<NBTOT, 256, 0, stream>>>(hist, rp, bsums);
    scan2<<<4, 1024, 0, stream>>>(bsums);
    scan3<<<(RPTOT + 255) / 256, 256, 0, stream>>>(rp, bsums);
    place4<<<(4 * NE_ + 255) / 256, 256, 0, stream>>>(ei_u2u, ei_t2t, ei_u2t, ei_t2u,
                                                      rp, fill, col);

    // ---- embeddings ----
    gemm_embed<32><<<8192, 256, 0, stream>>>(x_user, Wembu, bembu, hu, NU_, dflag);
    gemm_embed<64><<<8192, 256, 0, stream>>>(x_txn, Wembt, bembt, ht, NT_, dflag);

    const int gbU = (NU_ + 3) / 4;
    const int gbT = (NT_ + 3) / 4;

    for (int l = 0; l < NL; ++l) {
        const float* W0   = convWf + ((size_t)l * 4 + 0) * HD * HD;
        const float* Wt   = convWf + ((size_t)l * 4 + 1) * HD * HD;
        const float* Wu2t = convWf + ((size_t)l * 4 + 2) * HD * HD;
        const float* Wt2u = convWf + ((size_t)l * 4 + 3) * HD * HD;
        const float* B0   = convbf + ((size_t)l * 4 + 0) * HD;
        const float* Bt   = convbf + ((size_t)l * 4 + 1) * HD;
        const float* Bu2t = convbf + ((size_t)l * 4 + 2) * HD;
        const float* Bt2u = convbf + ((size_t)l * 4 + 3) * HD;

        // hu -> m_uu (u2u, scaled by dinv_u2u[src]) and m_ut (u2t, scaled by src out-deg)
        gemm_dual<<<8192, 256, 0, stream>>>(hu, W0, Wu2t, dinv + OFF0, dinv + OFF4,
                                            m_uu, m_ut, NU_);
        // ht -> m_tt (t2t) and m_tu (t2u)
        gemm_dual<<<8192, 256, 0, stream>>>(ht, Wt, Wt2u, dinv + OFF1, dinv + OFF5,
                                            m_tt, m_tu, NT_);

        // user update: u2u (self-loop) + t2u
        gather2<<<gbU, 256, 0, stream>>>(m_uu, m_tu,
                                         rp + OFF0, hist + OFF0, col + 0 * NE_, dinv + OFF0,
                                         rp + OFF3, hist + OFF3, col + 3 * NE_, dinv + OFF3,
                                         B0, Bt2u, hu, NU_);
        // txn update: t2t (self-loop) + u2t
        gather2<<<gbT, 256, 0, stream>>>(m_tt, m_ut,
                                         rp + OFF1, hist + OFF1, col + 1 * NE_, dinv + OFF1,
                                         rp + OFF2, hist + OFF2, col + 2 * NE_, dinv + OFF2,
                                         Bt, Bu2t, ht, NT_);
    }

    // ---- readout ----
    colmean<<<512, 256, 0, stream>>>(hu, NU_, 0.5f / NU_, gsum);
    colmean<<<512, 256, 0, stream>>>(ht, NT_, 0.5f / NT_, gsum);
    head<<<1, 64, 0, stream>>>(gsum, W1f, b1f, W2f, b2f, dflag, d_out);
}

// Round 5
// 2144.162 us; speedup vs baseline: 2.2366x; 1.1219x over previous
//
#include <hip/hip_runtime.h>
#include <hip/hip_bf16.h>
#include <hip/hip_fp8.h>

#define NU_ 100000
#define NT_ 200000
#define NE_ 1000000
#define HD  64
#define NL  3

// hist/dinv region offsets (node-keyed arrays)
#define OFF0 0                   // u2u dst (NU)  [selfloop]
#define OFF1 (NU_)               // t2t dst (NT)  [selfloop]
#define OFF2 (NU_ + NT_)         // u2t dst (NT)
#define OFF3 (NU_ + 2 * NT_)     // t2u dst (NU)
#define OFF4 (2 * NU_ + 2 * NT_) // u2t src (NU)
#define OFF5 (3 * NU_ + 2 * NT_) // t2u src (NT)
#define HTOT (3 * NU_ + 3 * NT_) // 900k
#define RPTOT (2 * NU_ + 2 * NT_) // 600k (first 4 regions)

// scan block partition (256/block)
#define NB0 391
#define NB1 782
#define CB1 391
#define CB2 1173
#define CB3 1955
#define NBTOT 2346

typedef float floatx2 __attribute__((ext_vector_type(2)));

// ---------------- fp8 helpers ----------------
__device__ __forceinline__ unsigned char enc_fp8(float v) {
    return (unsigned char)__hip_cvt_float_to_fp8(v, __HIP_SATFINITE, __HIP_E4M3);
}

__device__ __forceinline__ float dec1_fp8(unsigned int u) {
    int e = (u >> 3) & 15;
    int m = u & 7;
    int mant = m | (e ? 8 : 0);
    if (u & 0x80) mant = -mant;
    int ex = (e ? e : 1) - 10;
    return (float)mant * __uint_as_float((unsigned int)(ex + 127) << 23);
}

__device__ __forceinline__ void dec4_fp8(unsigned int u, float f[4]) {
#if __has_builtin(__builtin_amdgcn_cvt_pk_f32_fp8)
    floatx2 lo = __builtin_amdgcn_cvt_pk_f32_fp8((int)u, false);
    floatx2 hi = __builtin_amdgcn_cvt_pk_f32_fp8((int)u, true);
    f[0] = lo.x; f[1] = lo.y; f[2] = hi.x; f[3] = hi.y;
#else
    f[0] = dec1_fp8(u & 0xff);
    f[1] = dec1_fp8((u >> 8) & 0xff);
    f[2] = dec1_fp8((u >> 16) & 0xff);
    f[3] = dec1_fp8((u >> 24) & 0xff);
#endif
}

// ---------------- dtype detection ----------------
__global__ void detect_dtype(const unsigned short* __restrict__ x, int* __restrict__ flag, int n) {
    __shared__ int s_big;
    if (threadIdx.x == 0) s_big = 0;
    __syncthreads();
    int big = 0;
    for (int i = threadIdx.x; i < n; i += blockDim.x) {
        float v = __uint_as_float(((unsigned int)x[i]) << 16);
        if (!(fabsf(v) < 1.0e4f)) big = 1;
    }
    if (big) atomicAdd(&s_big, 1);
    __syncthreads();
    if (threadIdx.x == 0) flag[0] = (s_big > 0) ? 0 : 1;
}

// ---------------- fused weight conversion (+ gsum zero) ----------------
struct Ptr10 { const void* p[10]; };

__global__ void cvt_weights(Ptr10 src, float* __restrict__ dst, float* __restrict__ gsum,
                            const int* __restrict__ flag) {
    const int c[11] = {0, 2048, 2112, 6208, 6272, 55424, 56192, 60288, 60352, 60416, 60417};
    int i = blockIdx.x * blockDim.x + threadIdx.x;
    if (i < 64) gsum[i] = 0.f;
    if (i >= 60417) return;
    int r = 0;
#pragma unroll
    for (int k = 1; k < 10; ++k)
        if (i >= c[k]) r = k;
    int e = i - c[r];
    if (flag[0]) {
        unsigned short u = ((const unsigned short*)src.p[r])[e];
        dst[i] = __uint_as_float(((unsigned int)u) << 16);
    } else {
        dst[i] = ((const float*)src.p[r])[e];
    }
}

// ---------------- fused 6-way histogram ----------------
__global__ __launch_bounds__(256) void hist6(const int* __restrict__ a0, const int* __restrict__ a1,
                                             const int* __restrict__ a2, const int* __restrict__ a3,
                                             const int* __restrict__ a4, const int* __restrict__ a5,
                                             int* __restrict__ hist) {
    int gid = blockIdx.x * 256 + threadIdx.x;
    if (gid >= 6 * NE_) return;
    int r = gid / NE_;
    int e = gid - r * NE_;
    const int* a;
    int base;
    switch (r) {
        case 0: a = a0; base = OFF0; break;
        case 1: a = a1; base = OFF1; break;
        case 2: a = a2; base = OFF2; break;
        case 3: a = a3; base = OFF3; break;
        case 4: a = a4; base = OFF4; break;
        default: a = a5; base = OFF5; break;
    }
    atomicAdd(&hist[base + a[e]], 1);
}

// ---------------- dinv from histograms ----------------
__global__ void dinv_all(const int* __restrict__ hist, float* __restrict__ dinv) {
    int i = blockIdx.x * blockDim.x + threadIdx.x;
    if (i >= HTOT) return;
    int h = hist[i];
    float v;
    if (i < OFF2) v = rsqrtf((float)h + 1.0f);
    else v = (h > 0) ? rsqrtf((float)h) : 0.f;
    dinv[i] = v;
}

// ---------------- scan stage 1 ----------------
__global__ __launch_bounds__(256) void scan1(const int* __restrict__ hist, int* __restrict__ rp,
                                             int* __restrict__ bsums) {
    int b = blockIdx.x, t = threadIdx.x;
    int r, lb, base, n;
    if (b < CB1)      { r = 0; lb = b;       base = OFF0; n = NU_; }
    else if (b < CB2) { r = 1; lb = b - CB1; base = OFF1; n = NT_; }
    else if (b < CB3) { r = 2; lb = b - CB2; base = OFF2; n = NT_; }
    else              { r = 3; lb = b - CB3; base = OFF3; n = NU_; }
    int i = lb * 256 + t;
    int v = (i < n) ? hist[base + i] : 0;
    __shared__ int s[256];
    s[t] = v;
    __syncthreads();
    for (int off = 1; off < 256; off <<= 1) {
        int x = (t >= off) ? s[t - off] : 0;
        __syncthreads();
        s[t] += x;
        __syncthreads();
    }
    if (i < n) rp[base + i] = s[t] - v;
    if (t == 255) bsums[r * 1024 + lb] = s[255];
}

// ---------------- scan stage 2 ----------------
__global__ __launch_bounds__(1024) void scan2(int* __restrict__ bsums) {
    int r = blockIdx.x, t = threadIdx.x;
    const int nb = (r == 0 || r == 3) ? NB0 : NB1;
    int v = (t < nb) ? bsums[r * 1024 + t] : 0;
    __shared__ int s[1024];
    s[t] = v;
    __syncthreads();
    for (int off = 1; off < 1024; off <<= 1) {
        int x = (t >= off) ? s[t - off] : 0;
        __syncthreads();
        s[t] += x;
        __syncthreads();
    }
    if (t < nb) bsums[r * 1024 + t] = s[t] - v;
}

// ---------------- scan stage 3 ----------------
__global__ void scan3(int* __restrict__ rp, const int* __restrict__ bsums) {
    int gid = blockIdx.x * blockDim.x + threadIdx.x;
    if (gid >= RPTOT) return;
    int r, base;
    if (gid < OFF1)      { r = 0; base = OFF0; }
    else if (gid < OFF2) { r = 1; base = OFF1; }
    else if (gid < OFF3) { r = 2; base = OFF2; }
    else                 { r = 3; base = OFF3; }
    int lb = (gid - base) >> 8;
    rp[gid] += bsums[r * 1024 + lb];
}

// ---------------- CSR placement ----------------
__global__ __launch_bounds__(256) void place4(const int* __restrict__ e0, const int* __restrict__ e1,
                                              const int* __restrict__ e2, const int* __restrict__ e3,
                                              const int* __restrict__ rp, int* __restrict__ fill,
                                              int* __restrict__ col) {
    int gid = blockIdx.x * 256 + threadIdx.x;
    if (gid >= 4 * NE_) return;
    int r = gid / NE_;
    int e = gid - r * NE_;
    const int* ei;
    int base;
    switch (r) {
        case 0: ei = e0; base = OFF0; break;
        case 1: ei = e1; base = OFF1; break;
        case 2: ei = e2; base = OFF2; break;
        default: ei = e3; base = OFF3; break;
    }
    int s = ei[e];
    int d = ei[e + NE_];
    int pos = rp[base + d] + atomicAdd(&fill[base + d], 1);
    col[r * NE_ + pos] = s;
}

// ---------------- embedding GEMM (runtime dtype) ----------------
template <int K>
__global__ __launch_bounds__(256) void gemm_embed(const void* __restrict__ x,
                                                  const float* __restrict__ W,
                                                  const float* __restrict__ bias,
                                                  float* __restrict__ out, int N,
                                                  const int* __restrict__ flag) {
    const int lane = threadIdx.x & 63;
    float w[K];
#pragma unroll
    for (int k = 0; k < K; ++k) w[k] = W[k * HD + lane];
    const float b = bias[lane];
    const bool isb = flag[0] != 0;
    const int wid = (blockIdx.x << 2) + (threadIdx.x >> 6);
    const int stride = gridDim.x << 2;
    if (isb) {
        const unsigned short* xb = (const unsigned short*)x;
        for (int r = wid; r < N; r += stride) {
            const unsigned short* xr = xb + (size_t)r * K;
            float acc = b;
#pragma unroll
            for (int k = 0; k < K; ++k)
                acc = fmaf(__uint_as_float(((unsigned int)xr[k]) << 16), w[k], acc);
            out[(size_t)r * HD + lane] = acc;
        }
    } else {
        const float* xf = (const float*)x;
        for (int r = wid; r < N; r += stride) {
            const float* xr = xf + (size_t)r * K;
            float acc = b;
#pragma unroll
            for (int k = 0; k < K; ++k) acc = fmaf(xr[k], w[k], acc);
            out[(size_t)r * HD + lane] = acc;
        }
    }
}

// ---------------- dual-output GEMM: mA = fp8((h@WA)*scA), mB = fp8((h@WB)*scB)
__global__ __launch_bounds__(256) void gemm_dual(const float* __restrict__ h,
                                                 const float* __restrict__ WA,
                                                 const float* __restrict__ WB,
                                                 const float* __restrict__ scA,
                                                 const float* __restrict__ scB,
                                                 unsigned char* __restrict__ mA,
                                                 unsigned char* __restrict__ mB, int N) {
    const int lane = threadIdx.x & 63;
    float wa[HD], wb[HD];
#pragma unroll
    for (int k = 0; k < HD; ++k) wa[k] = WA[k * HD + lane];
#pragma unroll
    for (int k = 0; k < HD; ++k) wb[k] = WB[k * HD + lane];
    const int wid = (blockIdx.x << 2) + (threadIdx.x >> 6);
    const int stride = gridDim.x << 2;
    for (int r = wid; r < N; r += stride) {
        const float hv = h[(size_t)r * HD + lane];
        float accA = 0.f, accB = 0.f;
#pragma unroll
        for (int k = 0; k < HD; ++k) {
            float hk = __shfl(hv, k);
            accA = fmaf(hk, wa[k], accA);
            accB = fmaf(hk, wb[k], accB);
        }
        mA[(size_t)r * HD + lane] = enc_fp8(accA * scA[r]);
        mB[(size_t)r * HD + lane] = enc_fp8(accB * scB[r]);
    }
}

// ---------------- fused dual-relation gather (fp8 m) + selfloop + bias + relu
// wave = 1 dst; quad (16 lanes) handles one neighbor row; lane loads dword (4 cols).
__global__ __launch_bounds__(256) void gather2(const unsigned char* __restrict__ mA,
                                               const unsigned char* __restrict__ mB,
                                               const int* __restrict__ rpA,
                                               const int* __restrict__ cntA,
                                               const int* __restrict__ colA,
                                               const float* __restrict__ dA,
                                               const int* __restrict__ rpB,
                                               const int* __restrict__ cntB,
                                               const int* __restrict__ colB,
                                               const float* __restrict__ dB,
                                               const float* __restrict__ ba,
                                               const float* __restrict__ bb,
                                               float* __restrict__ out, int N) {
    const int lane = threadIdx.x & 63;
    const int quad = lane >> 4;
    const int sub = lane & 15;
    const int d = (blockIdx.x << 2) + (threadIdx.x >> 6);
    if (d >= N) return;

    float accA[4] = {0.f, 0.f, 0.f, 0.f};
    float accB[4] = {0.f, 0.f, 0.f, 0.f};

    // self-loop row on A side (quad 0 only, masked fma)
    {
        unsigned int u = *(const unsigned int*)(mA + ((size_t)d << 6) + (sub << 2));
        float f[4];
        dec4_fp8(u, f);
        float msk = (quad == 0) ? 1.f : 0.f;
#pragma unroll
        for (int k = 0; k < 4; ++k) accA[k] = fmaf(f[k], msk, accA[k]);
    }

    // A neighbor list
    {
        int st = rpA[d], cnt = cntA[d], done = 0;
        while (done < cnt) {
            int rem = cnt - done;
            if (rem > 64) rem = 64;
            int cidx = (lane < rem) ? colA[st + done + lane] : 0;
            int nch = (rem + 3) >> 2;
            for (int ch = 0; ch < nch; ++ch) {
                int j = (ch << 2) + quad;
                int c = __shfl(cidx, j);
                float msk = (j < rem) ? 1.f : 0.f;
                unsigned int u = *(const unsigned int*)(mA + ((size_t)c << 6) + (sub << 2));
                float f[4];
                dec4_fp8(u, f);
#pragma unroll
                for (int k = 0; k < 4; ++k) accA[k] = fmaf(f[k], msk, accA[k]);
            }
            done += rem;
        }
    }
    // B neighbor list
    {
        int st = rpB[d], cnt = cntB[d], done = 0;
        while (done < cnt) {
            int rem = cnt - done;
            if (rem > 64) rem = 64;
            int cidx = (lane < rem) ? colB[st + done + lane] : 0;
            int nch = (rem + 3) >> 2;
            for (int ch = 0; ch < nch; ++ch) {
                int j = (ch << 2) + quad;
                int c = __shfl(cidx, j);
                float msk = (j < rem) ? 1.f : 0.f;
                unsigned int u = *(const unsigned int*)(mB + ((size_t)c << 6) + (sub << 2));
                float f[4];
                dec4_fp8(u, f);
#pragma unroll
                for (int k = 0; k < 4; ++k) accB[k] = fmaf(f[k], msk, accB[k]);
            }
            done += rem;
        }
    }

    const float vA = dA[d], vB = dB[d];
    float r[4];
#pragma unroll
    for (int k = 0; k < 4; ++k) r[k] = vA * accA[k] + vB * accB[k];
#pragma unroll
    for (int k = 0; k < 4; ++k) r[k] += __shfl_xor(r[k], 16);
#pragma unroll
    for (int k = 0; k < 4; ++k) r[k] += __shfl_xor(r[k], 32);

    if (quad == 0) {
        const int col0 = sub << 2;
        const float4 b4a = *(const float4*)(ba + col0);
        const float4 b4b = *(const float4*)(bb + col0);
        float4 o;
        o.x = fmaxf(0.5f * (r[0] + b4a.x + b4b.x), 0.f);
        o.y = fmaxf(0.5f * (r[1] + b4a.y + b4b.y), 0.f);
        o.z = fmaxf(0.5f * (r[2] + b4a.z + b4b.z), 0.f);
        o.w = fmaxf(0.5f * (r[3] + b4a.w + b4b.w), 0.f);
        *(float4*)(out + ((size_t)d << 6) + col0) = o;
    }
}

// ---------------- column mean (scaled) into gsum[64] ----------------
__global__ __launch_bounds__(256) void colmean(const float* __restrict__ h, int n, float scale,
                                               float* __restrict__ gsum) {
    const int lane = threadIdx.x & 63;
    const int w = threadIdx.x >> 6;
    float s = 0.f;
    for (int r = blockIdx.x * 4 + w; r < n; r += gridDim.x * 4)
        s += h[(size_t)r * HD + lane];
    __shared__ float red[256];
    red[threadIdx.x] = s;
    __syncthreads();
    if (threadIdx.x < 64) {
        float t = red[threadIdx.x] + red[64 + threadIdx.x] + red[128 + threadIdx.x] +
                  red[192 + threadIdx.x];
        atomicAdd(&gsum[lane], t * scale);
    }
}

// ---------------- head MLP ----------------
__global__ void head(const float* __restrict__ g, const float* __restrict__ W1,
                     const float* __restrict__ b1, const float* __restrict__ W2,
                     const float* __restrict__ b2, const int* __restrict__ flag,
                     void* __restrict__ out) {
    const int c = threadIdx.x;
    float x = b1[c];
    for (int k = 0; k < HD; ++k) x = fmaf(g[k], W1[k * HD + c], x);
    x = fmaxf(x, 0.f);
    float t = x * W2[c];
    for (int off = 32; off; off >>= 1) t += __shfl_down(t, off);
    if (c == 0) {
        float z = t + b2[0];
        float s = 1.f / (1.f + expf(-z));
        if (flag[0]) *(__hip_bfloat16*)out = __float2bfloat16(s);
        else *(float*)out = s;
    }
}

extern "C" void kernel_launch(void* const* d_in, const int* in_sizes, int n_in,
                              void* d_out, int out_size, void* d_ws, size_t ws_size,
                              hipStream_t stream) {
    const void* x_user = d_in[0];
    const void* x_txn  = d_in[1];
    const int* ei_u2u = (const int*)d_in[2];
    const int* ei_t2t = (const int*)d_in[3];
    const int* ei_u2t = (const int*)d_in[4];
    const int* ei_t2u = (const int*)d_in[5];

    // ---- workspace layout ----
    float* ws = (float*)d_ws;
    float* hu = ws;                                   // NU*64 f32
    float* ht = hu + (size_t)NU_ * HD;                // NT*64 f32
    float* dinv = ht + (size_t)NT_ * HD;              // HTOT
    float* wts = dinv + HTOT;                         // 60417
    float* gsum = wts + 60417;                        // 64 (keeps 16B align after)
    float* gpad = gsum + 64;                          // pad to 16B boundary ok
    unsigned char* m_uu = (unsigned char*)gpad;       // NU*64 fp8
    unsigned char* m_ut = m_uu + (size_t)NU_ * HD;
    unsigned char* m_tt = m_ut + (size_t)NU_ * HD;
    unsigned char* m_tu = m_tt + (size_t)NT_ * HD;
    int* hist = (int*)(m_tu + (size_t)NT_ * HD);      // HTOT
    int* fill = hist + HTOT;                          // RPTOT
    int* rp   = fill + RPTOT;                         // RPTOT
    int* bsums = rp + RPTOT;                          // 4096
    int* col  = bsums + 4096;                         // 4*NE
    int* dflag = col + 4 * NE_;                       // 1

    // fp32 weight sub-pointers
    float* Wembu = wts;              // 2048
    float* bembu = Wembu + 2048;     // 64
    float* Wembt = bembu + 64;       // 4096
    float* bembt = Wembt + 4096;     // 64
    float* convWf = bembt + 64;      // 49152
    float* convbf = convWf + 49152;  // 768
    float* W1f = convbf + 768;       // 4096
    float* b1f = W1f + 4096;         // 64
    float* W2f = b1f + 64;           // 64
    float* b2f = W2f + 64;           // 1

    hipMemsetAsync(hist, 0, (size_t)(HTOT + RPTOT) * sizeof(int), stream);

    detect_dtype<<<1, 256, 0, stream>>>((const unsigned short*)x_user, dflag, 2048);
    {
        Ptr10 p;
        for (int k = 0; k < 10; ++k) p.p[k] = d_in[6 + k];
        cvt_weights<<<(60417 + 255) / 256, 256, 0, stream>>>(p, wts, gsum, dflag);
    }

    // ---- histograms, dinv, CSR ----
    hist6<<<(6 * NE_ + 255) / 256, 256, 0, stream>>>(ei_u2u + NE_, ei_t2t + NE_, ei_u2t + NE_,
                                                     ei_t2u + NE_, ei_u2t, ei_t2u, hist);
    dinv_all<<<(HTOT + 255) / 256, 256, 0, stream>>>(hist, dinv);
    scan1<<<NBTOT, 256, 0, stream>>>(hist, rp, bsums);
    scan2<<<4, 1024, 0, stream>>>(bsums);
    scan3<<<(RPTOT + 255) / 256, 256, 0, stream>>>(rp, bsums);
    place4<<<(4 * NE_ + 255) / 256, 256, 0, stream>>>(ei_u2u, ei_t2t, ei_u2t, ei_t2u,
                                                      rp, fill, col);

    // ---- embeddings ----
    gemm_embed<32><<<8192, 256, 0, stream>>>(x_user, Wembu, bembu, hu, NU_, dflag);
    gemm_embed<64><<<8192, 256, 0, stream>>>(x_txn, Wembt, bembt, ht, NT_, dflag);

    const int gbU = (NU_ + 3) / 4;
    const int gbT = (NT_ + 3) / 4;

    for (int l = 0; l < NL; ++l) {
        const float* W0   = convWf + ((size_t)l * 4 + 0) * HD * HD;
        const float* Wt   = convWf + ((size_t)l * 4 + 1) * HD * HD;
        const float* Wu2t = convWf + ((size_t)l * 4 + 2) * HD * HD;
        const float* Wt2u = convWf + ((size_t)l * 4 + 3) * HD * HD;
        const float* B0   = convbf + ((size_t)l * 4 + 0) * HD;
        const float* Bt   = convbf + ((size_t)l * 4 + 1) * HD;
        const float* Bu2t = convbf + ((size_t)l * 4 + 2) * HD;
        const float* Bt2u = convbf + ((size_t)l * 4 + 3) * HD;

        gemm_dual<<<8192, 256, 0, stream>>>(hu, W0, Wu2t, dinv + OFF0, dinv + OFF4,
                                            m_uu, m_ut, NU_);
        gemm_dual<<<8192, 256, 0, stream>>>(ht, Wt, Wt2u, dinv + OFF1, dinv + OFF5,
                                            m_tt, m_tu, NT_);

        // user update: u2u (self-loop) + t2u
        gather2<<<gbU, 256, 0, stream>>>(m_uu, m_tu,
                                         rp + OFF0, hist + OFF0, col + 0 * NE_, dinv + OFF0,
                                         rp + OFF3, hist + OFF3, col + 3 * NE_, dinv + OFF3,
                                         B0, Bt2u, hu, NU_);
        // txn update: t2t (self-loop) + u2t
        gather2<<<gbT, 256, 0, stream>>>(m_tt, m_ut,
                                         rp + OFF1, hist + OFF1, col + 1 * NE_, dinv + OFF1,
                                         rp + OFF2, hist + OFF2, col + 2 * NE_, dinv + OFF2,
                                         Bt, Bu2t, ht, NT_);
    }

    // ---- readout ----
    colmean<<<512, 256, 0, stream>>>(hu, NU_, 0.5f / NU_, gsum);
    colmean<<<512, 256, 0, stream>>>(ht, NT_, 0.5f / NT_, gsum);
    head<<<1, 64, 0, stream>>>(gsum, W1f, b1f, W2f, b2f, dflag, d_out);
}

// Round 6
// 1972.839 us; speedup vs baseline: 2.4308x; 1.0868x over previous
//
#include <hip/hip_runtime.h>
#include <hip/hip_bf16.h>
#include <hip/hip_fp8.h>

#define NU_ 100000
#define NT_ 200000
#define NE_ 1000000
#define HD  64
#define NL  3

// hist/dinv region offsets (node-keyed arrays)
#define OFF0 0                   // u2u dst (NU)  [selfloop]
#define OFF1 (NU_)               // t2t dst (NT)  [selfloop]
#define OFF2 (NU_ + NT_)         // u2t dst (NT)
#define OFF3 (NU_ + 2 * NT_)     // t2u dst (NU)
#define OFF4 (2 * NU_ + 2 * NT_) // u2t src (NU)
#define OFF5 (3 * NU_ + 2 * NT_) // t2u src (NT)
#define HTOT (3 * NU_ + 3 * NT_) // 900k
#define RPT2 (NU_ + NT_)         // merged rp/fill size (300k)

// merged scan partition (256/block): region0 user (391 blocks), region1 txn (782)
#define NBU 391
#define NBT 782
#define NBTOT2 (NBU + NBT)

typedef float floatx2 __attribute__((ext_vector_type(2)));

// ---------------- fp8 helpers ----------------
__device__ __forceinline__ unsigned char enc_fp8(float v) {
    return (unsigned char)__hip_cvt_float_to_fp8(v, __HIP_SATFINITE, __HIP_E4M3);
}

__device__ __forceinline__ float dec1_fp8(unsigned int u) {
    int e = (u >> 3) & 15;
    int m = u & 7;
    int mant = m | (e ? 8 : 0);
    if (u & 0x80) mant = -mant;
    int ex = (e ? e : 1) - 10;
    return (float)mant * __uint_as_float((unsigned int)(ex + 127) << 23);
}

__device__ __forceinline__ void dec4_fp8(unsigned int u, float* f) {
#if __has_builtin(__builtin_amdgcn_cvt_pk_f32_fp8)
    floatx2 lo = __builtin_amdgcn_cvt_pk_f32_fp8((int)u, false);
    floatx2 hi = __builtin_amdgcn_cvt_pk_f32_fp8((int)u, true);
    f[0] = lo.x; f[1] = lo.y; f[2] = hi.x; f[3] = hi.y;
#else
    f[0] = dec1_fp8(u & 0xff);
    f[1] = dec1_fp8((u >> 8) & 0xff);
    f[2] = dec1_fp8((u >> 16) & 0xff);
    f[3] = dec1_fp8((u >> 24) & 0xff);
#endif
}

// ---------------- dtype detection ----------------
__global__ void detect_dtype(const unsigned short* __restrict__ x, int* __restrict__ flag, int n) {
    __shared__ int s_big;
    if (threadIdx.x == 0) s_big = 0;
    __syncthreads();
    int big = 0;
    for (int i = threadIdx.x; i < n; i += blockDim.x) {
        float v = __uint_as_float(((unsigned int)x[i]) << 16);
        if (!(fabsf(v) < 1.0e4f)) big = 1;
    }
    if (big) atomicAdd(&s_big, 1);
    __syncthreads();
    if (threadIdx.x == 0) flag[0] = (s_big > 0) ? 0 : 1;
}

// ---------------- fused weight conversion (+ gsum zero) ----------------
struct Ptr10 { const void* p[10]; };

__global__ void cvt_weights(Ptr10 src, float* __restrict__ dst, float* __restrict__ gsum,
                            const int* __restrict__ flag) {
    const int c[11] = {0, 2048, 2112, 6208, 6272, 55424, 56192, 60288, 60352, 60416, 60417};
    int i = blockIdx.x * blockDim.x + threadIdx.x;
    if (i < 64) gsum[i] = 0.f;
    if (i >= 60417) return;
    int r = 0;
#pragma unroll
    for (int k = 1; k < 10; ++k)
        if (i >= c[k]) r = k;
    int e = i - c[r];
    if (flag[0]) {
        unsigned short u = ((const unsigned short*)src.p[r])[e];
        dst[i] = __uint_as_float(((unsigned int)u) << 16);
    } else {
        dst[i] = ((const float*)src.p[r])[e];
    }
}

// ---------------- fused 6-way histogram ----------------
__global__ __launch_bounds__(256) void hist6(const int* __restrict__ a0, const int* __restrict__ a1,
                                             const int* __restrict__ a2, const int* __restrict__ a3,
                                             const int* __restrict__ a4, const int* __restrict__ a5,
                                             int* __restrict__ hist) {
    int gid = blockIdx.x * 256 + threadIdx.x;
    if (gid >= 6 * NE_) return;
    int r = gid / NE_;
    int e = gid - r * NE_;
    const int* a;
    int base;
    switch (r) {
        case 0: a = a0; base = OFF0; break;
        case 1: a = a1; base = OFF1; break;
        case 2: a = a2; base = OFF2; break;
        case 3: a = a3; base = OFF3; break;
        case 4: a = a4; base = OFF4; break;
        default: a = a5; base = OFF5; break;
    }
    atomicAdd(&hist[base + a[e]], 1);
}

// ---------------- dinv from histograms ----------------
__global__ void dinv_all(const int* __restrict__ hist, float* __restrict__ dinv) {
    int i = blockIdx.x * blockDim.x + threadIdx.x;
    if (i >= HTOT) return;
    int h = hist[i];
    float v;
    if (i < OFF2) v = rsqrtf((float)h + 1.0f);
    else v = (h > 0) ? rsqrtf((float)h) : 0.f;
    dinv[i] = v;
}

// ---------------- merged scan stage 1: counts = hA[i]+hB[i] ----------------
__global__ __launch_bounds__(256) void scan1m(const int* __restrict__ hist, int* __restrict__ rp,
                                              int* __restrict__ bsums) {
    int b = blockIdx.x, t = threadIdx.x;
    int r, lb, n, rpbase, oA, oB;
    if (b < NBU) { r = 0; lb = b;       n = NU_; rpbase = 0;   oA = OFF0; oB = OFF3; }
    else         { r = 1; lb = b - NBU; n = NT_; rpbase = NU_; oA = OFF1; oB = OFF2; }
    int i = lb * 256 + t;
    int v = (i < n) ? hist[oA + i] + hist[oB + i] : 0;
    __shared__ int s[256];
    s[t] = v;
    __syncthreads();
    for (int off = 1; off < 256; off <<= 1) {
        int x = (t >= off) ? s[t - off] : 0;
        __syncthreads();
        s[t] += x;
        __syncthreads();
    }
    if (i < n) rp[rpbase + i] = s[t] - v;
    if (t == 255) bsums[r * 1024 + lb] = s[255];
}

// ---------------- merged scan stage 2 ----------------
__global__ __launch_bounds__(1024) void scan2m(int* __restrict__ bsums) {
    int r = blockIdx.x, t = threadIdx.x;
    const int nb = r ? NBT : NBU;
    int v = (t < nb) ? bsums[r * 1024 + t] : 0;
    __shared__ int s[1024];
    s[t] = v;
    __syncthreads();
    for (int off = 1; off < 1024; off <<= 1) {
        int x = (t >= off) ? s[t - off] : 0;
        __syncthreads();
        s[t] += x;
        __syncthreads();
    }
    if (t < nb) bsums[r * 1024 + t] = s[t] - v;
}

// ---------------- merged scan stage 3 ----------------
__global__ void scan3m(int* __restrict__ rp, const int* __restrict__ bsums) {
    int gid = blockIdx.x * blockDim.x + threadIdx.x;
    if (gid >= RPT2) return;
    int r = (gid < NU_) ? 0 : 1;
    int base = r ? NU_ : 0;
    int lb = (gid - base) >> 8;
    rp[gid] += bsums[r * 1024 + lb];
}

// ---------------- merged CSR placement (tag bit 31 = relation B) ------------
__global__ __launch_bounds__(256) void place4m(const int* __restrict__ e_u2u,
                                               const int* __restrict__ e_t2t,
                                               const int* __restrict__ e_u2t,
                                               const int* __restrict__ e_t2u,
                                               const int* __restrict__ rp, int* __restrict__ fill,
                                               int* __restrict__ colU, int* __restrict__ colT) {
    int gid = blockIdx.x * 256 + threadIdx.x;
    if (gid >= 4 * NE_) return;
    int r = gid / NE_;
    int e = gid - r * NE_;
    const int* ei;
    int rpo;
    unsigned int tag;
    int* cl;
    switch (r) {
        case 0: ei = e_u2u; rpo = 0;   tag = 0u;          cl = colU; break;  // user A
        case 1: ei = e_t2u; rpo = 0;   tag = 0x80000000u; cl = colU; break;  // user B
        case 2: ei = e_t2t; rpo = NU_; tag = 0u;          cl = colT; break;  // txn A
        default: ei = e_u2t; rpo = NU_; tag = 0x80000000u; cl = colT; break; // txn B
    }
    int s = ei[e];
    int d = ei[e + NE_];
    int pos = rp[rpo + d] + atomicAdd(&fill[rpo + d], 1);
    cl[pos] = (int)((unsigned int)s | tag);
}

// ---------------- embedding GEMM (runtime dtype) ----------------
template <int K>
__global__ __launch_bounds__(256) void gemm_embed(const void* __restrict__ x,
                                                  const float* __restrict__ W,
                                                  const float* __restrict__ bias,
                                                  float* __restrict__ out, int N,
                                                  const int* __restrict__ flag) {
    const int lane = threadIdx.x & 63;
    float w[K];
#pragma unroll
    for (int k = 0; k < K; ++k) w[k] = W[k * HD + lane];
    const float b = bias[lane];
    const bool isb = flag[0] != 0;
    const int wid = (blockIdx.x << 2) + (threadIdx.x >> 6);
    const int stride = gridDim.x << 2;
    if (isb) {
        const unsigned short* xb = (const unsigned short*)x;
        for (int r = wid; r < N; r += stride) {
            const unsigned short* xr = xb + (size_t)r * K;
            float acc = b;
#pragma unroll
            for (int k = 0; k < K; ++k)
                acc = fmaf(__uint_as_float(((unsigned int)xr[k]) << 16), w[k], acc);
            out[(size_t)r * HD + lane] = acc;
        }
    } else {
        const float* xf = (const float*)x;
        for (int r = wid; r < N; r += stride) {
            const float* xr = xf + (size_t)r * K;
            float acc = b;
#pragma unroll
            for (int k = 0; k < K; ++k) acc = fmaf(xr[k], w[k], acc);
            out[(size_t)r * HD + lane] = acc;
        }
    }
}

// ---------------- dual-output GEMM: mA = fp8((h@WA)*scA), mB = fp8((h@WB)*scB)
__global__ __launch_bounds__(256) void gemm_dual(const float* __restrict__ h,
                                                 const float* __restrict__ WA,
                                                 const float* __restrict__ WB,
                                                 const float* __restrict__ scA,
                                                 const float* __restrict__ scB,
                                                 unsigned char* __restrict__ mA,
                                                 unsigned char* __restrict__ mB, int N) {
    const int lane = threadIdx.x & 63;
    float wa[HD], wb[HD];
#pragma unroll
    for (int k = 0; k < HD; ++k) wa[k] = WA[k * HD + lane];
#pragma unroll
    for (int k = 0; k < HD; ++k) wb[k] = WB[k * HD + lane];
    const int wid = (blockIdx.x << 2) + (threadIdx.x >> 6);
    const int stride = gridDim.x << 2;
    for (int r = wid; r < N; r += stride) {
        const float hv = h[(size_t)r * HD + lane];
        float accA = 0.f, accB = 0.f;
#pragma unroll
        for (int k = 0; k < HD; ++k) {
            float hk = __shfl(hv, k);
            accA = fmaf(hk, wa[k], accA);
            accB = fmaf(hk, wb[k], accB);
        }
        mA[(size_t)r * HD + lane] = enc_fp8(accA * scA[r]);
        mB[(size_t)r * HD + lane] = enc_fp8(accB * scB[r]);
    }
}

// ---------------- merged-CSR gather, 8-deep software pipeline ----------------
// wave = 1 dst; 8 groups of 8 lanes; lane loads uint2 (8 fp8) -> 8 rows/inst.
// col tag bit31: 0 -> mA (scale dA), 1 -> mB (scale dB). Self-loop on A side.
__global__ __launch_bounds__(256) void gather2m(const unsigned char* __restrict__ mA,
                                                const unsigned char* __restrict__ mB,
                                                const int* __restrict__ rp,
                                                const int* __restrict__ cA,
                                                const int* __restrict__ cB,
                                                const int* __restrict__ col,
                                                const float* __restrict__ dAv_,
                                                const float* __restrict__ dBv_,
                                                const float* __restrict__ ba,
                                                const float* __restrict__ bb,
                                                float* __restrict__ out, int N) {
    const int lane = threadIdx.x & 63;
    const int grp = lane >> 3;          // 0..7: which row of the chunk
    const int sub = lane & 7;           // 0..7: 8B slice within row
    const int d = (blockIdx.x << 2) + (threadIdx.x >> 6);
    if (d >= N) return;

    const float dA = dAv_[d];
    const float dB = dBv_[d];
    float acc[8] = {0.f, 0.f, 0.f, 0.f, 0.f, 0.f, 0.f, 0.f};

    // self-loop row (A side), issued first, consumed last
    const uint2 uself = *(const uint2*)(mA + ((size_t)d << 6) + (sub << 3));

    int st = rp[d];
    int cnt = cA[d] + cB[d];
    int done = 0;
    while (done < cnt) {
        int rem = cnt - done;
        if (rem > 64) rem = 64;
        int cw = (lane < rem) ? col[st + done + lane] : 0;
        const int nch = (rem + 7) >> 3;

        uint2 ub0, ub1, ub2, ub3;
        float sc0, sc1, sc2, sc3;

        auto issue = [&](int p, uint2& ub, float& sc) {
            int j = (p << 3) + grp;
            unsigned int c = (unsigned int)__shfl(cw, j);
            const unsigned char* base = (c >> 31) ? mB : mA;
            float sv = (c >> 31) ? dB : dA;
            unsigned int idx = c & 0x7fffffffu;
            sc = (j < rem) ? sv : 0.f;
            ub = *(const uint2*)(base + ((size_t)idx << 6) + (sub << 3));
        };
        auto consume = [&](uint2 u, float s) {
            float f[8];
            dec4_fp8(u.x, f);
            dec4_fp8(u.y, f + 4);
#pragma unroll
            for (int k = 0; k < 8; ++k) acc[k] = fmaf(f[k], s, acc[k]);
        };

        issue(0, ub0, sc0);
        if (nch > 1) issue(1, ub1, sc1);
        if (nch > 2) issue(2, ub2, sc2);
        if (nch > 3) issue(3, ub3, sc3);

        consume(ub0, sc0);
        if (nch > 4) issue(4, ub0, sc0);
        if (nch > 1) consume(ub1, sc1);
        if (nch > 5) issue(5, ub1, sc1);
        if (nch > 2) consume(ub2, sc2);
        if (nch > 6) issue(6, ub2, sc2);
        if (nch > 3) consume(ub3, sc3);
        if (nch > 7) issue(7, ub3, sc3);
        if (nch > 4) consume(ub0, sc0);
        if (nch > 5) consume(ub1, sc1);
        if (nch > 6) consume(ub2, sc2);
        if (nch > 7) consume(ub3, sc3);

        done += rem;
    }

    // self-loop contribution (groups other than 0 masked)
    {
        float f[8];
        dec4_fp8(uself.x, f);
        dec4_fp8(uself.y, f + 4);
        const float s = (grp == 0) ? dA : 0.f;
#pragma unroll
        for (int k = 0; k < 8; ++k) acc[k] = fmaf(f[k], s, acc[k]);
    }

    // reduce across the 8 groups
#pragma unroll
    for (int k = 0; k < 8; ++k) {
        acc[k] += __shfl_xor(acc[k], 8);
        acc[k] += __shfl_xor(acc[k], 16);
        acc[k] += __shfl_xor(acc[k], 32);
    }

    if (grp == 0) {
        const int col0 = sub << 3;
        float o[8];
#pragma unroll
        for (int k = 0; k < 8; ++k)
            o[k] = fmaxf(0.5f * (acc[k] + ba[col0 + k] + bb[col0 + k]), 0.f);
        float4 v0 = {o[0], o[1], o[2], o[3]};
        float4 v1 = {o[4], o[5], o[6], o[7]};
        *(float4*)(out + ((size_t)d << 6) + col0) = v0;
        *(float4*)(out + ((size_t)d << 6) + col0 + 4) = v1;
    }
}

// ---------------- column mean (scaled) into gsum[64] ----------------
__global__ __launch_bounds__(256) void colmean(const float* __restrict__ h, int n, float scale,
                                               float* __restrict__ gsum) {
    const int lane = threadIdx.x & 63;
    const int w = threadIdx.x >> 6;
    float s = 0.f;
    for (int r = blockIdx.x * 4 + w; r < n; r += gridDim.x * 4)
        s += h[(size_t)r * HD + lane];
    __shared__ float red[256];
    red[threadIdx.x] = s;
    __syncthreads();
    if (threadIdx.x < 64) {
        float t = red[threadIdx.x] + red[64 + threadIdx.x] + red[128 + threadIdx.x] +
                  red[192 + threadIdx.x];
        atomicAdd(&gsum[lane], t * scale);
    }
}

// ---------------- head MLP ----------------
__global__ void head(const float* __restrict__ g, const float* __restrict__ W1,
                     const float* __restrict__ b1, const float* __restrict__ W2,
                     const float* __restrict__ b2, const int* __restrict__ flag,
                     void* __restrict__ out) {
    const int c = threadIdx.x;
    float x = b1[c];
    for (int k = 0; k < HD; ++k) x = fmaf(g[k], W1[k * HD + c], x);
    x = fmaxf(x, 0.f);
    float t = x * W2[c];
    for (int off = 32; off; off >>= 1) t += __shfl_down(t, off);
    if (c == 0) {
        float z = t + b2[0];
        float s = 1.f / (1.f + expf(-z));
        if (flag[0]) *(__hip_bfloat16*)out = __float2bfloat16(s);
        else *(float*)out = s;
    }
}

extern "C" void kernel_launch(void* const* d_in, const int* in_sizes, int n_in,
                              void* d_out, int out_size, void* d_ws, size_t ws_size,
                              hipStream_t stream) {
    const void* x_user = d_in[0];
    const void* x_txn  = d_in[1];
    const int* ei_u2u = (const int*)d_in[2];
    const int* ei_t2t = (const int*)d_in[3];
    const int* ei_u2t = (const int*)d_in[4];
    const int* ei_t2u = (const int*)d_in[5];

    // ---- workspace layout (16B-aligned fp8 arrays) ----
    float* ws = (float*)d_ws;
    float* hu = ws;                                   // NU*64 f32
    float* ht = hu + (size_t)NU_ * HD;                // NT*64 f32
    float* dinv = ht + (size_t)NT_ * HD;              // HTOT (900000)
    float* wts = dinv + HTOT;                         // 60432 (padded to /16)
    float* gsum = wts + 60432;                        // 64
    unsigned char* m_uu = (unsigned char*)(gsum + 64);  // NU*64 fp8 (16B aligned)
    unsigned char* m_ut = m_uu + (size_t)NU_ * HD;
    unsigned char* m_tt = m_ut + (size_t)NU_ * HD;
    unsigned char* m_tu = m_tt + (size_t)NT_ * HD;
    int* hist = (int*)(m_tu + (size_t)NT_ * HD);      // HTOT
    int* fill = hist + HTOT;                          // RPT2 (300k)
    int* rp   = fill + RPT2;                          // RPT2
    int* bsums = rp + RPT2;                           // 2048
    int* colU = bsums + 2048;                         // 2M
    int* colT = colU + 2 * NE_;                       // 2M
    int* dflag = colT + 2 * NE_;                      // 1

    // fp32 weight sub-pointers
    float* Wembu = wts;              // 2048
    float* bembu = Wembu + 2048;     // 64
    float* Wembt = bembu + 64;       // 4096
    float* bembt = Wembt + 4096;     // 64
    float* convWf = bembt + 64;      // 49152
    float* convbf = convWf + 49152;  // 768
    float* W1f = convbf + 768;       // 4096
    float* b1f = W1f + 4096;         // 64
    float* W2f = b1f + 64;           // 64
    float* b2f = W2f + 64;           // 1

    hipMemsetAsync(hist, 0, (size_t)(HTOT + RPT2) * sizeof(int), stream);

    detect_dtype<<<1, 256, 0, stream>>>((const unsigned short*)x_user, dflag, 2048);
    {
        Ptr10 p;
        for (int k = 0; k < 10; ++k) p.p[k] = d_in[6 + k];
        cvt_weights<<<(60417 + 255) / 256, 256, 0, stream>>>(p, wts, gsum, dflag);
    }

    // ---- histograms, dinv, merged CSR ----
    hist6<<<(6 * NE_ + 255) / 256, 256, 0, stream>>>(ei_u2u + NE_, ei_t2t + NE_, ei_u2t + NE_,
                                                     ei_t2u + NE_, ei_u2t, ei_t2u, hist);
    dinv_all<<<(HTOT + 255) / 256, 256, 0, stream>>>(hist, dinv);
    scan1m<<<NBTOT2, 256, 0, stream>>>(hist, rp, bsums);
    scan2m<<<2, 1024, 0, stream>>>(bsums);
    scan3m<<<(RPT2 + 255) / 256, 256, 0, stream>>>(rp, bsums);
    place4m<<<(4 * NE_ + 255) / 256, 256, 0, stream>>>(ei_u2u, ei_t2t, ei_u2t, ei_t2u,
                                                       rp, fill, colU, colT);

    // ---- embeddings ----
    gemm_embed<32><<<8192, 256, 0, stream>>>(x_user, Wembu, bembu, hu, NU_, dflag);
    gemm_embed<64><<<8192, 256, 0, stream>>>(x_txn, Wembt, bembt, ht, NT_, dflag);

    const int gbU = (NU_ + 3) / 4;
    const int gbT = (NT_ + 3) / 4;

    for (int l = 0; l < NL; ++l) {
        const float* W0   = convWf + ((size_t)l * 4 + 0) * HD * HD;
        const float* Wt   = convWf + ((size_t)l * 4 + 1) * HD * HD;
        const float* Wu2t = convWf + ((size_t)l * 4 + 2) * HD * HD;
        const float* Wt2u = convWf + ((size_t)l * 4 + 3) * HD * HD;
        const float* B0   = convbf + ((size_t)l * 4 + 0) * HD;
        const float* Bt   = convbf + ((size_t)l * 4 + 1) * HD;
        const float* Bu2t = convbf + ((size_t)l * 4 + 2) * HD;
        const float* Bt2u = convbf + ((size_t)l * 4 + 3) * HD;

        gemm_dual<<<8192, 256, 0, stream>>>(hu, W0, Wu2t, dinv + OFF0, dinv + OFF4,
                                            m_uu, m_ut, NU_);
        gemm_dual<<<8192, 256, 0, stream>>>(ht, Wt, Wt2u, dinv + OFF1, dinv + OFF5,
                                            m_tt, m_tu, NT_);

        // user update: A = u2u (self-loop), B = t2u
        gather2m<<<gbU, 256, 0, stream>>>(m_uu, m_tu, rp, hist + OFF0, hist + OFF3, colU,
                                          dinv + OFF0, dinv + OFF3, B0, Bt2u, hu, NU_);
        // txn update: A = t2t (self-loop), B = u2t
        gather2m<<<gbT, 256, 0, stream>>>(m_tt, m_ut, rp + NU_, hist + OFF1, hist + OFF2, colT,
                                          dinv + OFF1, dinv + OFF2, Bt, Bu2t, ht, NT_);
    }

    // ---- readout ----
    colmean<<<512, 256, 0, stream>>>(hu, NU_, 0.5f / NU_, gsum);
    colmean<<<512, 256, 0, stream>>>(ht, NT_, 0.5f / NT_, gsum);
    head<<<1, 64, 0, stream>>>(gsum, W1f, b1f, W2f, b2f, dflag, d_out);
}